// Round 1
// baseline (267.786 us; speedup 1.0000x reference)
//
#include <hip/hip_runtime.h>

#define DIN 128
#define SLOTS 56   // max deg cap; P(Poisson(16) > 56) ~ 2e-14/node. Multiple of 4.

// ---------------------------------------------------------------------------
// out = round(clip( A^2 (X w1f) + c1*(A 1) + c0 , 0, 10)),  A = D^-1/2 (W+I) D^-1/2
// w2f = W2@fcw, w1f = W1@w2f, c1 = b1·w2f, c0 = b2·fcw + fcb.
//
// Scattered-op cost model (rounds 3-9): every scattered op ~1/(20-45 G/s);
// coalesced traffic ~free. Round 10 change: the list-push + dependent chain
// walk (atomicExch + 1 scattered *latency-chained* read/edge) is replaced by
// DIRECT SLOT PLACEMENT: p = atomicAdd(&cnt[d],1); slotsT[p*n+d] = {src,ew}.
// Scattered ops/edge: K2 = 1 atomic + 1 fire-and-forget write (no latency
// chain), K3 = 0 (fully coalesced), K4/K5 = 1 scattered pk gather each (the
// irreducible A^2 cost). ed[] (25.6 MB written + chain-read) is eliminated.
//   K1: fold head weights -> w1f, c0, c1; cnt[] = 0
//   K2: per-edge direct slot scatter (+ gemv q -> pk1.x)
//   K3: coalesced: wsum from own slots -> dis; pad row to x4; cnt4;
//       pk1={q,dis}; pk2={c1+dis^2 q, dis}
//   K4: slot spmv: pk2.x += sum nm*q[s]        (1 scattered pk1 load/edge)
//   K5: slot spmv + head: u = c0+dis^2 t+sum nm*t[s]; out=round(clip(u,0,10))
// f64 node values; f32 norm/deg math matches the reference.
// ---------------------------------------------------------------------------

__global__ void precompute_kernel(const float* __restrict__ W1, const float* __restrict__ b1,
                                  const float* __restrict__ W2, const float* __restrict__ b2,
                                  const float* __restrict__ fcw, const float* __restrict__ fcb,
                                  double* __restrict__ w1f, double* __restrict__ cvals,
                                  int* __restrict__ cnt, int n) {
    const int t = threadIdx.x;
    if (blockIdx.x > 0) {
        int i = (blockIdx.x - 1) * 256 + t;
        if (i < n) cnt[i] = 0;
        return;
    }
    __shared__ double sw2f[64];
    if (t < 64) {
        double s = 0.0;
        for (int j = 0; j < 64; j++) s += (double)W2[t * 64 + j] * (double)fcw[j];
        sw2f[t] = s;
    }
    __syncthreads();
    if (t < 128) {
        double s = 0.0;
        for (int j = 0; j < 64; j++) s += (double)W1[t * 64 + j] * sw2f[j];
        w1f[t] = s;
    }
    if (t == 128) {
        double c1 = 0.0, c0 = (double)fcb[0];
        for (int j = 0; j < 64; j++) {
            c1 += (double)b1[j] * sw2f[j];
            c0 += (double)b2[j] * (double)fcw[j];
        }
        cvals[0] = c0;
        cvals[1] = c1;
    }
}

// blocks [0,eblk): per-edge direct slot scatter (1 scattered atomic to cnt,
// L2-resident 400KB; 1 scattered non-blocking 8B write to slotsT);
// blocks [eblk,..): gemv q -> pk1[row].x
__global__ __launch_bounds__(256) void scatter_gemv_kernel(
        const int* __restrict__ src, const int* __restrict__ dst,
        const float* __restrict__ ew, const float* __restrict__ X,
        const double* __restrict__ w1f, int* __restrict__ cnt,
        uint2* __restrict__ slotsT, double2* __restrict__ pk1,
        int n, int e, int eblk) {
    const int blk = blockIdx.x;
    const int t = threadIdx.x;
    if (blk < eblk) {
        int i = blk * 256 + t;
        if (i < e) {
            int d = dst[i];
            int p = atomicAdd(&cnt[d], 1);       // the one scattered atomic
            if (p < SLOTS)
                slotsT[(long)p * n + d] =        // fire-and-forget scattered write
                    uint2{(unsigned)src[i], __float_as_uint(ew[i])};
        }
        return;
    }
    long g = (long)(blk - eblk) * 256 + t;
    int row = (int)(g >> 6);
    int lane = (int)(g & 63);
    if (row >= n) return;
    float2 x = *(const float2*)(X + (long)row * DIN + 2 * lane);  // 512B/wave coalesced
    double v = (double)x.x * w1f[2 * lane] + (double)x.y * w1f[2 * lane + 1];
#pragma unroll
    for (int off = 32; off > 0; off >>= 1) v += __shfl_down(v, off, 64);
    if (lane == 0) pk1[row].x = v;
}

// thread-per-node, FULLY COALESCED: wsum from own slot row -> deg -> dis;
// pad row to x4; cnt4; pk1={q,dis}; pk2={c1+dis^2 q, dis}.
__global__ __launch_bounds__(256) void setup_kernel(
        const int* __restrict__ cnt, uint2* __restrict__ slotsT,
        int* __restrict__ cnt4, const double* __restrict__ cvals,
        double2* __restrict__ pk1, double2* __restrict__ pk2, int n) {
    int i = blockIdx.x * 256 + threadIdx.x;
    if (i >= n) return;
    int c = min(cnt[i], SLOTS);
    float wsum = 0.0f;
    for (int p = 0; p < c; p++)
        wsum += __uint_as_float(slotsT[(long)p * n + i].y);   // coalesced
    int p4 = (c + 3) & ~3;
    for (int p = c; p < p4; p++)
        slotsT[(long)p * n + i] = uint2{0u, 0u};  // pad: src=0, ew=0 -> nm=0
    cnt4[i] = p4;
    float d = 1.0f + wsum;  // self-loop weight 1
    float di = (d > 0.0f) ? (1.0f / sqrtf(fmaxf(d, 1e-12f))) : 0.0f;
    double qv = pk1[i].x;
    pk1[i] = double2{qv, (double)di};
    pk2[i] = double2{cvals[1] + (double)(di * di) * qv, (double)di};
}

// thread-per-node: pk2[i].x += sum nm * q[s]; slots coalesced, pk1[s] scattered
__global__ __launch_bounds__(256) void spmv1_kernel(
        const int* __restrict__ cnt4, const uint2* __restrict__ slotsT,
        const double2* __restrict__ pk1, double2* __restrict__ pk2, int n) {
    int i = blockIdx.x * 256 + threadIdx.x;
    if (i >= n) return;
    int c4 = cnt4[i];
    double2 me = pk2[i];
    float di = (float)me.y;
    double acc = me.x;
    for (int p = 0; p < c4; p += 4) {
        uint2 s0 = slotsT[(long)(p + 0) * n + i];
        uint2 s1 = slotsT[(long)(p + 1) * n + i];
        uint2 s2 = slotsT[(long)(p + 2) * n + i];
        uint2 s3 = slotsT[(long)(p + 3) * n + i];
        double2 a0 = pk1[s0.x];  // one 16B scattered L2 load: {q, dis}
        double2 a1 = pk1[s1.x];
        double2 a2 = pk1[s2.x];
        double2 a3 = pk1[s3.x];
        acc += (double)((float)a0.y * __uint_as_float(s0.y) * di) * a0.x;
        acc += (double)((float)a1.y * __uint_as_float(s1.y) * di) * a1.x;
        acc += (double)((float)a2.y * __uint_as_float(s2.y) * di) * a2.x;
        acc += (double)((float)a3.y * __uint_as_float(s3.y) * di) * a3.x;
    }
    pk2[i].x = acc;
}

// thread-per-node: u = c0 + dis^2*t + sum nm*t[s]; out = round(clip(u,0,10))
__global__ __launch_bounds__(256) void spmv2_head_kernel(
        const int* __restrict__ cnt4, const uint2* __restrict__ slotsT,
        const double2* __restrict__ pk2, const double* __restrict__ cvals,
        float* __restrict__ out, int n) {
    int i = blockIdx.x * 256 + threadIdx.x;
    if (i >= n) return;
    int c4 = cnt4[i];
    double2 me = pk2[i];
    float di = (float)me.y;
    double acc = cvals[0] + (double)(di * di) * me.x;
    for (int p = 0; p < c4; p += 4) {
        uint2 s0 = slotsT[(long)(p + 0) * n + i];
        uint2 s1 = slotsT[(long)(p + 1) * n + i];
        uint2 s2 = slotsT[(long)(p + 2) * n + i];
        uint2 s3 = slotsT[(long)(p + 3) * n + i];
        double2 a0 = pk2[s0.x];  // {t, dis}
        double2 a1 = pk2[s1.x];
        double2 a2 = pk2[s2.x];
        double2 a3 = pk2[s3.x];
        acc += (double)((float)a0.y * __uint_as_float(s0.y) * di) * a0.x;
        acc += (double)((float)a1.y * __uint_as_float(s1.y) * di) * a1.x;
        acc += (double)((float)a2.y * __uint_as_float(s2.y) * di) * a2.x;
        acc += (double)((float)a3.y * __uint_as_float(s3.y) * di) * a3.x;
    }
    float o = (float)acc;
    o = fminf(fmaxf(o, 0.0f), 10.0f);
    out[i] = rintf(o);  // v_rndne_f32: half-to-even, matches jnp.round
}

extern "C" void kernel_launch(void* const* d_in, const int* in_sizes, int n_in,
                              void* d_out, int out_size, void* d_ws, size_t ws_size,
                              hipStream_t stream) {
    const float* x   = (const float*)d_in[0];  // [N, 128]
    const int*   eix = (const int*)d_in[1];    // [2, E]
    const float* ew  = (const float*)d_in[2];  // [E]
    const float* W1  = (const float*)d_in[3];  // [128, 64]
    const float* b1  = (const float*)d_in[4];  // [64]
    const float* W2  = (const float*)d_in[5];  // [64, 64]
    const float* b2  = (const float*)d_in[6];  // [64]
    const float* fcw = (const float*)d_in[7];  // [64]
    const float* fcb = (const float*)d_in[8];  // [1]
    float* out = (float*)d_out;                // [N]

    const int n = in_sizes[0] / DIN;
    const int e = in_sizes[2];
    const int* src = eix;
    const int* dst = eix + e;

    // workspace layout (8-byte units, 512B-aligned regions); ~50 MB
    auto al = [](size_t v) { return (v + 63) & ~(size_t)63; };
    double* ws = (double*)d_ws;
    size_t o = 0;
    double*  w1f   = ws + o; o += al(DIN);
    double*  cvals = ws + o; o += al(2);
    double2* pk1   = (double2*)(ws + o); o += al((size_t)n * 2);
    double2* pk2   = (double2*)(ws + o); o += al((size_t)n * 2);
    int*     cnt   = (int*)(ws + o);     o += al(((size_t)n + 1) / 2);
    int*     cnt4  = (int*)(ws + o);     o += al(((size_t)n + 1) / 2);
    uint2*   slotsT = (uint2*)(ws + o);  // n * SLOTS * 8B = 44.8 MB

    const int nblk = (n + 255) / 256;
    const int eblk = (e + 255) / 256;
    const int gemvblk = (n + 3) / 4;   // 4 rows (waves) per block

    precompute_kernel<<<1 + nblk, 256, 0, stream>>>(W1, b1, W2, b2, fcw, fcb,
                                                    w1f, cvals, cnt, n);
    scatter_gemv_kernel<<<eblk + gemvblk, 256, 0, stream>>>(src, dst, ew, x, w1f,
                                                            cnt, slotsT, pk1, n, e, eblk);
    setup_kernel<<<nblk, 256, 0, stream>>>(cnt, slotsT, cnt4, cvals, pk1, pk2, n);
    spmv1_kernel<<<nblk, 256, 0, stream>>>(cnt4, slotsT, pk1, pk2, n);
    spmv2_head_kernel<<<nblk, 256, 0, stream>>>(cnt4, slotsT, pk2, cvals, out, n);
}

// Round 2
// 260.166 us; speedup vs baseline: 1.0293x; 1.0293x over previous
//
#include <hip/hip_runtime.h>

#define DIN 128
#define SLOTS 56   // max deg cap; P(Poisson(16) > 56) ~ 2e-14/node. Multiple of 4.

// ---------------------------------------------------------------------------
// out = round(clip( A^2 (X w1f) + c1*(A 1) + c0 , 0, 10)),  A = D^-1/2 (W+I) D^-1/2
// w2f = W2@fcw, w1f = W1@w2f, c1 = b1·w2f, c0 = b2·fcw + fcb.
//
// Scattered-op cost model (rounds 3-10): scattered ops ~1/(20-45 G/s);
// coalesced traffic ~free; scattered WRITES are cheap only into L2-resident
// regions (round-10 lesson: 8B scatter into 44.8MB slotsT cost +53us).
// Round 11: round-0 structure (list push + chain walk + slot compaction) with
// head[] PADDED to one int per 64B line (stride hs=16, 6.4MB, L2-resident).
// Theory: 400KB head = 256 atomics/line -> L2 line-lock serialization was
// the 94us scatter bottleneck; padding gives 1 hot addr/line.
//   K1: fold head weights -> w1f, c0, c1; head[] = -1
//   K2: per-edge list-push, ed[i]={next,src,ew} coalesced (+ gemv q -> pk1.x)
//   K3: walk chains once: deg -> dis; COMPACT to slotsT[p*n+i]={src,ew};
//       pad row to x4; cnt4; pk1={q,dis}; pk2={c1+dis^2 q, dis}
//   K4: slot spmv: pk2.x += sum nm*q[s]        (1 scattered pk1 load/edge)
//   K5: slot spmv + head: u = c0+dis^2 t+sum nm*t[s]; out=round(clip(u,0,10))
// f64 node values; f32 norm/deg math matches the reference.
// ---------------------------------------------------------------------------

__global__ void precompute_kernel(const float* __restrict__ W1, const float* __restrict__ b1,
                                  const float* __restrict__ W2, const float* __restrict__ b2,
                                  const float* __restrict__ fcw, const float* __restrict__ fcb,
                                  double* __restrict__ w1f, double* __restrict__ cvals,
                                  int* __restrict__ head, int n, int hs) {
    const int t = threadIdx.x;
    if (blockIdx.x > 0) {
        int i = (blockIdx.x - 1) * 256 + t;
        if (i < n) head[(long)i * hs] = -1;
        return;
    }
    __shared__ double sw2f[64];
    if (t < 64) {
        double s = 0.0;
        for (int j = 0; j < 64; j++) s += (double)W2[t * 64 + j] * (double)fcw[j];
        sw2f[t] = s;
    }
    __syncthreads();
    if (t < 128) {
        double s = 0.0;
        for (int j = 0; j < 64; j++) s += (double)W1[t * 64 + j] * sw2f[j];
        w1f[t] = s;
    }
    if (t == 128) {
        double c1 = 0.0, c0 = (double)fcb[0];
        for (int j = 0; j < 64; j++) {
            c1 += (double)b1[j] * sw2f[j];
            c0 += (double)b2[j] * (double)fcw[j];
        }
        cvals[0] = c0;
        cvals[1] = c1;
    }
}

// blocks [0,eblk): per-edge list push (1 scattered atomic, L2-resident padded
// head; payload written COALESCED at ed[i]); blocks [eblk,..): gemv q -> pk1.x
__global__ __launch_bounds__(256) void scatter_gemv_kernel(
        const int* __restrict__ src, const int* __restrict__ dst,
        const float* __restrict__ ew, const float* __restrict__ X,
        const double* __restrict__ w1f, int* __restrict__ head,
        uint4* __restrict__ ed, double2* __restrict__ pk1,
        int n, int e, int eblk, int hs) {
    const int blk = blockIdx.x;
    const int t = threadIdx.x;
    if (blk < eblk) {
        int i = blk * 256 + t;
        if (i < e) {
            int d = dst[i];
            int old = atomicExch(&head[(long)d * hs], i);   // the one scattered op
            ed[i] = uint4{(unsigned)old, (unsigned)src[i], __float_as_uint(ew[i]), 0u};
        }
        return;
    }
    long g = (long)(blk - eblk) * 256 + t;
    int row = (int)(g >> 6);
    int lane = (int)(g & 63);
    if (row >= n) return;
    float2 x = *(const float2*)(X + (long)row * DIN + 2 * lane);  // 512B/wave coalesced
    double v = (double)x.x * w1f[2 * lane] + (double)x.y * w1f[2 * lane + 1];
#pragma unroll
    for (int off = 32; off > 0; off >>= 1) v += __shfl_down(v, off, 64);
    if (lane == 0) pk1[row].x = v;
}

// thread-per-node chain walk (1 scattered ed read per edge, done ONCE):
// deg -> dis; compact chain into slotsT (coalesced: lockstep hop p); pk1/pk2.
__global__ __launch_bounds__(256) void walk_compact_kernel(
        const int* __restrict__ head, const uint4* __restrict__ ed,
        uint2* __restrict__ slotsT, int* __restrict__ cnt4,
        const double* __restrict__ cvals,
        double2* __restrict__ pk1, double2* __restrict__ pk2, int n, int hs) {
    int i = blockIdx.x * 256 + threadIdx.x;
    if (i >= n) return;
    int cur = head[(long)i * hs];
    float wsum = 0.0f;
    int c = 0;
    while (cur >= 0) {
        uint4 v = ed[cur];                    // one 16B scattered read per hop
        wsum += __uint_as_float(v.z);
        if (c < SLOTS) slotsT[(long)c * n + i] = uint2{v.y, v.z};  // coalesced
        c++;
        cur = (int)v.x;
    }
    c = min(c, SLOTS);
    int p4 = (c + 3) & ~3;
    for (int p = c; p < p4; p++)
        slotsT[(long)p * n + i] = uint2{0u, 0u};  // pad: src=0, ew=0 -> nm=0
    cnt4[i] = p4;
    float d = 1.0f + wsum;  // self-loop weight 1
    float di = (d > 0.0f) ? (1.0f / sqrtf(fmaxf(d, 1e-12f))) : 0.0f;
    double qv = pk1[i].x;
    pk1[i] = double2{qv, (double)di};
    pk2[i] = double2{cvals[1] + (double)(di * di) * qv, (double)di};
}

// thread-per-node: pk2[i].x += sum nm * q[s]; slots coalesced, pk1[s] scattered
__global__ __launch_bounds__(256) void spmv1_kernel(
        const int* __restrict__ cnt4, const uint2* __restrict__ slotsT,
        const double2* __restrict__ pk1, double2* __restrict__ pk2, int n) {
    int i = blockIdx.x * 256 + threadIdx.x;
    if (i >= n) return;
    int c4 = cnt4[i];
    double2 me = pk2[i];
    float di = (float)me.y;
    double acc = me.x;
    for (int p = 0; p < c4; p += 4) {
        uint2 s0 = slotsT[(long)(p + 0) * n + i];
        uint2 s1 = slotsT[(long)(p + 1) * n + i];
        uint2 s2 = slotsT[(long)(p + 2) * n + i];
        uint2 s3 = slotsT[(long)(p + 3) * n + i];
        double2 a0 = pk1[s0.x];  // one 16B scattered L2 load: {q, dis}
        double2 a1 = pk1[s1.x];
        double2 a2 = pk1[s2.x];
        double2 a3 = pk1[s3.x];
        acc += (double)((float)a0.y * __uint_as_float(s0.y) * di) * a0.x;
        acc += (double)((float)a1.y * __uint_as_float(s1.y) * di) * a1.x;
        acc += (double)((float)a2.y * __uint_as_float(s2.y) * di) * a2.x;
        acc += (double)((float)a3.y * __uint_as_float(s3.y) * di) * a3.x;
    }
    pk2[i].x = acc;
}

// thread-per-node: u = c0 + dis^2*t + sum nm*t[s]; out = round(clip(u,0,10))
__global__ __launch_bounds__(256) void spmv2_head_kernel(
        const int* __restrict__ cnt4, const uint2* __restrict__ slotsT,
        const double2* __restrict__ pk2, const double* __restrict__ cvals,
        float* __restrict__ out, int n) {
    int i = blockIdx.x * 256 + threadIdx.x;
    if (i >= n) return;
    int c4 = cnt4[i];
    double2 me = pk2[i];
    float di = (float)me.y;
    double acc = cvals[0] + (double)(di * di) * me.x;
    for (int p = 0; p < c4; p += 4) {
        uint2 s0 = slotsT[(long)(p + 0) * n + i];
        uint2 s1 = slotsT[(long)(p + 1) * n + i];
        uint2 s2 = slotsT[(long)(p + 2) * n + i];
        uint2 s3 = slotsT[(long)(p + 3) * n + i];
        double2 a0 = pk2[s0.x];  // {t, dis}
        double2 a1 = pk2[s1.x];
        double2 a2 = pk2[s2.x];
        double2 a3 = pk2[s3.x];
        acc += (double)((float)a0.y * __uint_as_float(s0.y) * di) * a0.x;
        acc += (double)((float)a1.y * __uint_as_float(s1.y) * di) * a1.x;
        acc += (double)((float)a2.y * __uint_as_float(s2.y) * di) * a2.x;
        acc += (double)((float)a3.y * __uint_as_float(s3.y) * di) * a3.x;
    }
    float o = (float)acc;
    o = fminf(fmaxf(o, 0.0f), 10.0f);
    out[i] = rintf(o);  // v_rndne_f32: half-to-even, matches jnp.round
}

extern "C" void kernel_launch(void* const* d_in, const int* in_sizes, int n_in,
                              void* d_out, int out_size, void* d_ws, size_t ws_size,
                              hipStream_t stream) {
    const float* x   = (const float*)d_in[0];  // [N, 128]
    const int*   eix = (const int*)d_in[1];    // [2, E]
    const float* ew  = (const float*)d_in[2];  // [E]
    const float* W1  = (const float*)d_in[3];  // [128, 64]
    const float* b1  = (const float*)d_in[4];  // [64]
    const float* W2  = (const float*)d_in[5];  // [64, 64]
    const float* b2  = (const float*)d_in[6];  // [64]
    const float* fcw = (const float*)d_in[7];  // [64]
    const float* fcb = (const float*)d_in[8];  // [1]
    float* out = (float*)d_out;                // [N]

    const int n = in_sizes[0] / DIN;
    const int e = in_sizes[2];
    const int* src = eix;
    const int* dst = eix + e;

    // workspace layout (8-byte units, 512B-aligned regions)
    auto al = [](size_t v) { return (v + 63) & ~(size_t)63; };
    auto layout = [&](int hs, double* ws, double** w1f, double** cvals,
                      double2** pk1, double2** pk2, int** head, int** cnt4,
                      uint4** ed, uint2** slotsT) -> size_t {
        size_t o = 0;
        *w1f   = ws + o; o += al(DIN);
        *cvals = ws + o; o += al(2);
        *pk1   = (double2*)(ws + o); o += al((size_t)n * 2);
        *pk2   = (double2*)(ws + o); o += al((size_t)n * 2);
        *head  = (int*)(ws + o);     o += al(((size_t)n * hs + 1) / 2);
        *cnt4  = (int*)(ws + o);     o += al(((size_t)n + 1) / 2);
        *ed    = (uint4*)(ws + o);   o += al((size_t)e * 2);      // 25.6 MB
        *slotsT = (uint2*)(ws + o);  o += (size_t)n * SLOTS;      // 44.8 MB
        return o * 8;  // bytes
    };

    double* ws = (double*)d_ws;
    double *w1f, *cvals;
    double2 *pk1, *pk2;
    int *head, *cnt4;
    uint4* ed;
    uint2* slotsT;
    int hs = 16;  // one head per 64B line -> no L2 line-lock contention
    if (layout(hs, ws, &w1f, &cvals, &pk1, &pk2, &head, &cnt4, &ed, &slotsT) > ws_size)
        hs = 1;   // tight workspace: fall back to round-0 packed head
    layout(hs, ws, &w1f, &cvals, &pk1, &pk2, &head, &cnt4, &ed, &slotsT);

    const int nblk = (n + 255) / 256;
    const int eblk = (e + 255) / 256;
    const int gemvblk = (n + 3) / 4;   // 4 rows (waves) per block

    precompute_kernel<<<1 + nblk, 256, 0, stream>>>(W1, b1, W2, b2, fcw, fcb,
                                                    w1f, cvals, head, n, hs);
    scatter_gemv_kernel<<<eblk + gemvblk, 256, 0, stream>>>(src, dst, ew, x, w1f,
                                                            head, ed, pk1, n, e, eblk, hs);
    walk_compact_kernel<<<nblk, 256, 0, stream>>>(head, ed, slotsT, cnt4, cvals,
                                                  pk1, pk2, n, hs);
    spmv1_kernel<<<nblk, 256, 0, stream>>>(cnt4, slotsT, pk1, pk2, n);
    spmv2_head_kernel<<<nblk, 256, 0, stream>>>(cnt4, slotsT, pk2, cvals, out, n);
}

// Round 3
// 252.323 us; speedup vs baseline: 1.0613x; 1.0311x over previous
//
#include <hip/hip_runtime.h>

#define DIN 128
#define SLOTS 56   // max deg cap; P(Poisson(16) > 56) ~ 2e-14/node. Multiple of 8.
#define EPT 4      // edges per thread in scatter phase (independent atomic chains)

// ---------------------------------------------------------------------------
// out = round(clip( A^2 (X w1f) + c1*(A 1) + c0 , 0, 10)),  A = D^-1/2 (W+I) D^-1/2
// w2f = W2@fcw, w1f = W1@w2f, c1 = b1·w2f, c0 = b2·fcw + fcb.
//
// Scattered-op cost model v2 (rounds 0-2 evidence): scattered ops hit a
// ~20-45 G/s wall that is LATENCY-CAPPED (inflight/latency), not
// contention-capped (line padding changed nothing, r2) and not helped by
// moving writes to big regions (r1: +53us for 8B scatter into 44.8MB).
// Lever: memory-level parallelism per thread -> independent atomic chains.
//   K1: fold head weights -> w1f, c0, c1; head[] = -1
//   K2: per-edge list-push, EPT=4 independent atomicExch per thread;
//       ed[i]={next,src,ew} coalesced (+ gemv q -> pk1.x)
//   K3: walk chains once: deg -> dis; COMPACT to slotsT[p*n+i]={src,ew};
//       pad row to x8; cnt4; pk1={q,dis}; pk2={c1+dis^2 q, dis}
//   K4: slot spmv: pk2.x += sum nm*q[s]   (8 independent gathers in flight)
//   K5: slot spmv + head: u = c0+dis^2 t+sum nm*t[s]; out=round(clip(u,0,10))
// f64 node values; f32 norm/deg math matches the reference.
// ---------------------------------------------------------------------------

__global__ void precompute_kernel(const float* __restrict__ W1, const float* __restrict__ b1,
                                  const float* __restrict__ W2, const float* __restrict__ b2,
                                  const float* __restrict__ fcw, const float* __restrict__ fcb,
                                  double* __restrict__ w1f, double* __restrict__ cvals,
                                  int* __restrict__ head, int n) {
    const int t = threadIdx.x;
    if (blockIdx.x > 0) {
        int i = (blockIdx.x - 1) * 256 + t;
        if (i < n) head[i] = -1;
        return;
    }
    __shared__ double sw2f[64];
    if (t < 64) {
        double s = 0.0;
        for (int j = 0; j < 64; j++) s += (double)W2[t * 64 + j] * (double)fcw[j];
        sw2f[t] = s;
    }
    __syncthreads();
    if (t < 128) {
        double s = 0.0;
        for (int j = 0; j < 64; j++) s += (double)W1[t * 64 + j] * sw2f[j];
        w1f[t] = s;
    }
    if (t == 128) {
        double c1 = 0.0, c0 = (double)fcb[0];
        for (int j = 0; j < 64; j++) {
            c1 += (double)b1[j] * sw2f[j];
            c0 += (double)b2[j] * (double)fcw[j];
        }
        cvals[0] = c0;
        cvals[1] = c1;
    }
}

// blocks [0,sblk): per-thread EPT-edge list push. Loads coalesced (stride T);
// EPT independent atomicExch issued back-to-back (4x inflight per wave);
// ed payload written coalesced. blocks [sblk,..): gemv q -> pk1[row].x
__global__ __launch_bounds__(256) void scatter_gemv_kernel(
        const int* __restrict__ src, const int* __restrict__ dst,
        const float* __restrict__ ew, const float* __restrict__ X,
        const double* __restrict__ w1f, int* __restrict__ head,
        uint4* __restrict__ ed, double2* __restrict__ pk1,
        int n, int e, int sblk) {
    const int blk = blockIdx.x;
    const int t = threadIdx.x;
    if (blk < sblk) {
        const int T = sblk * 256;          // total scatter threads
        const int i0 = blk * 256 + t;
        int d[EPT], s[EPT], old[EPT];
        float w[EPT];
        bool ok[EPT];
#pragma unroll
        for (int k = 0; k < EPT; k++) {    // coalesced loads
            int i = i0 + k * T;
            ok[k] = (i < e);
            if (ok[k]) { d[k] = dst[i]; s[k] = src[i]; w[k] = ew[i]; }
        }
#pragma unroll
        for (int k = 0; k < EPT; k++)      // EPT independent scattered atomics
            if (ok[k]) old[k] = atomicExch(&head[d[k]], i0 + k * T);
#pragma unroll
        for (int k = 0; k < EPT; k++)      // coalesced payload stores
            if (ok[k]) ed[i0 + k * T] =
                uint4{(unsigned)old[k], (unsigned)s[k], __float_as_uint(w[k]), 0u};
        return;
    }
    long g = (long)(blk - sblk) * 256 + t;
    int row = (int)(g >> 6);
    int lane = (int)(g & 63);
    if (row >= n) return;
    float2 x = *(const float2*)(X + (long)row * DIN + 2 * lane);  // 512B/wave coalesced
    double v = (double)x.x * w1f[2 * lane] + (double)x.y * w1f[2 * lane + 1];
#pragma unroll
    for (int off = 32; off > 0; off >>= 1) v += __shfl_down(v, off, 64);
    if (lane == 0) pk1[row].x = v;
}

// thread-per-node chain walk (1 scattered ed read per edge, done ONCE):
// deg -> dis; compact chain into slotsT (coalesced: lockstep hop p); pk1/pk2.
__global__ __launch_bounds__(256) void walk_compact_kernel(
        const int* __restrict__ head, const uint4* __restrict__ ed,
        uint2* __restrict__ slotsT, int* __restrict__ cnt4,
        const double* __restrict__ cvals,
        double2* __restrict__ pk1, double2* __restrict__ pk2, int n) {
    int i = blockIdx.x * 256 + threadIdx.x;
    if (i >= n) return;
    int cur = head[i];
    float wsum = 0.0f;
    int c = 0;
    while (cur >= 0) {
        uint4 v = ed[cur];                    // one 16B scattered read per hop
        wsum += __uint_as_float(v.z);
        if (c < SLOTS) slotsT[(long)c * n + i] = uint2{v.y, v.z};  // coalesced
        c++;
        cur = (int)v.x;
    }
    c = min(c, SLOTS);
    int p8 = (c + 7) & ~7;                    // pad to x8 for spmv ILP
    for (int p = c; p < p8; p++)
        slotsT[(long)p * n + i] = uint2{0u, 0u};  // pad: src=0, ew=0 -> nm=0
    cnt4[i] = p8;
    float d = 1.0f + wsum;  // self-loop weight 1
    float di = (d > 0.0f) ? (1.0f / sqrtf(fmaxf(d, 1e-12f))) : 0.0f;
    double qv = pk1[i].x;
    pk1[i] = double2{qv, (double)di};
    pk2[i] = double2{cvals[1] + (double)(di * di) * qv, (double)di};
}

// thread-per-node: pk2[i].x += sum nm * q[s]; slots coalesced, pk1[s] scattered
// 8 independent gathers in flight per iteration (MLP for the latency wall).
__global__ __launch_bounds__(256) void spmv1_kernel(
        const int* __restrict__ cnt4, const uint2* __restrict__ slotsT,
        const double2* __restrict__ pk1, double2* __restrict__ pk2, int n) {
    int i = blockIdx.x * 256 + threadIdx.x;
    if (i >= n) return;
    int c8 = cnt4[i];
    double2 me = pk2[i];
    float di = (float)me.y;
    double acc = me.x;
    for (int p = 0; p < c8; p += 8) {
        uint2 s[8];
        double2 a[8];
#pragma unroll
        for (int k = 0; k < 8; k++) s[k] = slotsT[(long)(p + k) * n + i];
#pragma unroll
        for (int k = 0; k < 8; k++) a[k] = pk1[s[k].x];  // 8 scattered L2 loads
#pragma unroll
        for (int k = 0; k < 8; k++)
            acc += (double)((float)a[k].y * __uint_as_float(s[k].y) * di) * a[k].x;
    }
    pk2[i].x = acc;
}

// thread-per-node: u = c0 + dis^2*t + sum nm*t[s]; out = round(clip(u,0,10))
__global__ __launch_bounds__(256) void spmv2_head_kernel(
        const int* __restrict__ cnt4, const uint2* __restrict__ slotsT,
        const double2* __restrict__ pk2, const double* __restrict__ cvals,
        float* __restrict__ out, int n) {
    int i = blockIdx.x * 256 + threadIdx.x;
    if (i >= n) return;
    int c8 = cnt4[i];
    double2 me = pk2[i];
    float di = (float)me.y;
    double acc = cvals[0] + (double)(di * di) * me.x;
    for (int p = 0; p < c8; p += 8) {
        uint2 s[8];
        double2 a[8];
#pragma unroll
        for (int k = 0; k < 8; k++) s[k] = slotsT[(long)(p + k) * n + i];
#pragma unroll
        for (int k = 0; k < 8; k++) a[k] = pk2[s[k].x];  // 8 scattered L2 loads
#pragma unroll
        for (int k = 0; k < 8; k++)
            acc += (double)((float)a[k].y * __uint_as_float(s[k].y) * di) * a[k].x;
    }
    float o = (float)acc;
    o = fminf(fmaxf(o, 0.0f), 10.0f);
    out[i] = rintf(o);  // v_rndne_f32: half-to-even, matches jnp.round
}

extern "C" void kernel_launch(void* const* d_in, const int* in_sizes, int n_in,
                              void* d_out, int out_size, void* d_ws, size_t ws_size,
                              hipStream_t stream) {
    const float* x   = (const float*)d_in[0];  // [N, 128]
    const int*   eix = (const int*)d_in[1];    // [2, E]
    const float* ew  = (const float*)d_in[2];  // [E]
    const float* W1  = (const float*)d_in[3];  // [128, 64]
    const float* b1  = (const float*)d_in[4];  // [64]
    const float* W2  = (const float*)d_in[5];  // [64, 64]
    const float* b2  = (const float*)d_in[6];  // [64]
    const float* fcw = (const float*)d_in[7];  // [64]
    const float* fcb = (const float*)d_in[8];  // [1]
    float* out = (float*)d_out;                // [N]

    const int n = in_sizes[0] / DIN;
    const int e = in_sizes[2];
    const int* src = eix;
    const int* dst = eix + e;

    // workspace layout (8-byte units, 512B-aligned regions); ~74 MB
    auto al = [](size_t v) { return (v + 63) & ~(size_t)63; };
    double* ws = (double*)d_ws;
    size_t o = 0;
    double*  w1f   = ws + o; o += al(DIN);
    double*  cvals = ws + o; o += al(2);
    double2* pk1   = (double2*)(ws + o); o += al((size_t)n * 2);
    double2* pk2   = (double2*)(ws + o); o += al((size_t)n * 2);
    int*     head  = (int*)(ws + o);     o += al(((size_t)n + 1) / 2);
    int*     cnt4  = (int*)(ws + o);     o += al(((size_t)n + 1) / 2);
    uint4*   ed    = (uint4*)(ws + o);   o += al((size_t)e * 2);      // 25.6 MB
    uint2*   slotsT = (uint2*)(ws + o);  // n * SLOTS * 8B = 44.8 MB

    const int nblk = (n + 255) / 256;
    const int sblk = (e + 256 * EPT - 1) / (256 * EPT);  // scatter blocks
    const int gemvblk = (n + 3) / 4;   // 4 rows (waves) per block

    precompute_kernel<<<1 + nblk, 256, 0, stream>>>(W1, b1, W2, b2, fcw, fcb,
                                                    w1f, cvals, head, n);
    scatter_gemv_kernel<<<sblk + gemvblk, 256, 0, stream>>>(src, dst, ew, x, w1f,
                                                            head, ed, pk1, n, e, sblk);
    walk_compact_kernel<<<nblk, 256, 0, stream>>>(head, ed, slotsT, cnt4, cvals,
                                                  pk1, pk2, n);
    spmv1_kernel<<<nblk, 256, 0, stream>>>(cnt4, slotsT, pk1, pk2, n);
    spmv2_head_kernel<<<nblk, 256, 0, stream>>>(cnt4, slotsT, pk2, cvals, out, n);
}

// Round 4
// 213.790 us; speedup vs baseline: 1.2526x; 1.1802x over previous
//
#include <hip/hip_runtime.h>

#define DIN 128
#define BINW 128        // nodes per bin
#define BINSHIFT 7
#define NB_MAX 1024     // supports n <= 131072
#define CHUNK 8192      // edges per binning block (256 thr x 32 iters)

// ---------------------------------------------------------------------------
// out = round(clip( A^2 (X w1f) + c1*(A 1) + c0 , 0, 10)),  A = D^-1/2 (W+I) D^-1/2
// w2f = W2@fcw, w1f = W1@w2f, c1 = b1·w2f, c0 = b2·fcw + fcb.
//
// Scattered-op cost model v3 (rounds 0-3): per-edge global scattered ATOMICS
// are a ~20 G/s chip-level wall -- invariant to address padding (r2) and to
// per-thread MLP (r3). Scattered READS run ~35-45 G/s and pipeline. Scattered
// writes are cheap only with L2-resident merge frontier (r1).
// => Build adjacency with a 2-level counting sort whose global atomics are
// per-(block,bin) [153K total, not 1.6M], all edge traffic coalesced; spmv
// accumulates per-node in LDS. Only irreducible scattered ops remain: the two
// 1.6M pk-gather reads. No degree caps anywhere (exact algorithm).
//   K1 prep:     w1f, c0, c1; binCnt = 0
//   K2 hist+gemv: LDS hist of dst>>7 per 8192-edge chunk (+ gemv q -> pk1.x)
//   K3 scan:     binBase = exscan(binCnt); binCur = binBase
//   K4 binscatter: per chunk: LDS hist -> reserve runs (1 atomic/bin/block)
//                -> place edges {src|dlow<<20, ew} at run positions
//   K5 setup:    per bin: wsum via LDS f32 atomics -> dis; pk1={q,dis};
//                pk2={c1+dis^2 q, dis}
//   K6 spmv1:    per bin: acc[dlow] += f64(f32(dis_s*ew))*q_s (LDS f64 atomic);
//                pk2.x += dis_d * acc
//   K7 spmv2:    same with pk2 gather; u = c0+dis^2 t+dis*acc; out=round(clip)
// ---------------------------------------------------------------------------

__global__ void precompute_kernel(const float* __restrict__ W1, const float* __restrict__ b1,
                                  const float* __restrict__ W2, const float* __restrict__ b2,
                                  const float* __restrict__ fcw, const float* __restrict__ fcb,
                                  double* __restrict__ w1f, double* __restrict__ cvals,
                                  unsigned* __restrict__ binCnt, int nb) {
    const int t = threadIdx.x;
    if (blockIdx.x > 0) {
        int i = (blockIdx.x - 1) * 256 + t;
        if (i < nb) binCnt[i] = 0u;
        return;
    }
    __shared__ double sw2f[64];
    if (t < 64) {
        double s = 0.0;
        for (int j = 0; j < 64; j++) s += (double)W2[t * 64 + j] * (double)fcw[j];
        sw2f[t] = s;
    }
    __syncthreads();
    if (t < 128) {
        double s = 0.0;
        for (int j = 0; j < 64; j++) s += (double)W1[t * 64 + j] * sw2f[j];
        w1f[t] = s;
    }
    if (t == 128) {
        double c1 = 0.0, c0 = (double)fcb[0];
        for (int j = 0; j < 64; j++) {
            c1 += (double)b1[j] * sw2f[j];
            c0 += (double)b2[j] * (double)fcw[j];
        }
        cvals[0] = c0;
        cvals[1] = c1;
    }
}

// blocks [0,hblk): LDS histogram of CHUNK edges -> global atomicAdd per bin
// (782 atomics/block, not 8192). blocks [hblk,..): gemv q -> pk1[row].x
__global__ __launch_bounds__(256) void hist_gemv_kernel(
        const int* __restrict__ dst, const float* __restrict__ X,
        const double* __restrict__ w1f, unsigned* __restrict__ binCnt,
        double2* __restrict__ pk1, int n, int e, int nb, int hblk) {
    __shared__ unsigned cnt[NB_MAX];
    const int blk = blockIdx.x;
    const int t = threadIdx.x;
    if (blk < hblk) {
        for (int b = t; b < nb; b += 256) cnt[b] = 0u;
        __syncthreads();
        const long base = (long)blk * CHUNK;
        for (int k = 0; k < CHUNK / 256; k++) {
            long i = base + k * 256 + t;
            if (i < e) atomicAdd(&cnt[dst[i] >> BINSHIFT], 1u);
        }
        __syncthreads();
        for (int b = t; b < nb; b += 256) {
            unsigned c = cnt[b];
            if (c) atomicAdd(&binCnt[b], c);
        }
        return;
    }
    long g = (long)(blk - hblk) * 256 + t;
    int row = (int)(g >> 6);
    int lane = (int)(g & 63);
    if (row >= n) return;
    float2 x = *(const float2*)(X + (long)row * DIN + 2 * lane);  // coalesced
    double v = (double)x.x * w1f[2 * lane] + (double)x.y * w1f[2 * lane + 1];
#pragma unroll
    for (int off = 32; off > 0; off >>= 1) v += __shfl_down(v, off, 64);
    if (lane == 0) pk1[row].x = v;
}

// 1 block: exclusive scan of binCnt[nb] -> binBase[nb+1]; binCur = binBase
__global__ void scan_kernel(const unsigned* __restrict__ binCnt,
                            unsigned* __restrict__ binBase,
                            unsigned* __restrict__ binCur, int nb) {
    __shared__ unsigned part[256];
    const int t = threadIdx.x;
    unsigned loc[4];
    unsigned s = 0;
#pragma unroll
    for (int k = 0; k < 4; k++) {
        int idx = t * 4 + k;
        unsigned v = (idx < nb) ? binCnt[idx] : 0u;
        loc[k] = s;
        s += v;
    }
    part[t] = s;
    __syncthreads();
    if (t == 0) {
        unsigned run = 0;
        for (int j = 0; j < 256; j++) { unsigned v = part[j]; part[j] = run; run += v; }
    }
    __syncthreads();
    unsigned p = part[t];
#pragma unroll
    for (int k = 0; k < 4; k++) {
        int idx = t * 4 + k;
        if (idx < nb) { binBase[idx] = p + loc[k]; binCur[idx] = p + loc[k]; }
    }
    if (t == 255) binBase[nb] = p + s;
}

// per CHUNK: LDS hist -> one global atomicAdd per (block,bin) reserving a run
// -> place edges at run positions (plain 8B stores, run-local frontier).
__global__ __launch_bounds__(256) void binscatter_kernel(
        const int* __restrict__ src, const int* __restrict__ dst,
        const float* __restrict__ ew, unsigned* __restrict__ binCur,
        uint2* __restrict__ binned, int e, int nb) {
    __shared__ unsigned cnt[NB_MAX];
    __shared__ unsigned rb[NB_MAX];
    const int blk = blockIdx.x;
    const int t = threadIdx.x;
    for (int b = t; b < nb; b += 256) cnt[b] = 0u;
    __syncthreads();
    const long base = (long)blk * CHUNK;
    for (int k = 0; k < CHUNK / 256; k++) {
        long i = base + k * 256 + t;
        if (i < e) atomicAdd(&cnt[dst[i] >> BINSHIFT], 1u);
    }
    __syncthreads();
    for (int b = t; b < nb; b += 256) {
        unsigned c = cnt[b];
        rb[b] = c ? atomicAdd(&binCur[b], c) : 0u;   // per-(block,bin) reservation
        cnt[b] = 0u;                                  // reuse as local offset
    }
    __syncthreads();
    for (int k = 0; k < CHUNK / 256; k++) {
        long i = base + k * 256 + t;
        if (i < e) {
            int d = dst[i];
            int b = d >> BINSHIFT;
            unsigned p = rb[b] + atomicAdd(&cnt[b], 1u);
            binned[p] = uint2{(unsigned)src[i] | ((unsigned)(d & (BINW - 1)) << 20),
                              __float_as_uint(ew[i])};
        }
    }
}

// per bin: wsum[dlow] += ew (LDS f32 atomics, coalesced edge reads) -> dis;
// pk1={q,dis}; pk2={c1+dis^2 q, dis}
__global__ __launch_bounds__(256) void setup_kernel(
        const uint2* __restrict__ binned, const unsigned* __restrict__ binBase,
        const double* __restrict__ cvals,
        double2* __restrict__ pk1, double2* __restrict__ pk2, int n) {
    __shared__ float ws[BINW];
    const int b = blockIdx.x;
    const int t = threadIdx.x;
    if (t < BINW) ws[t] = 0.0f;
    __syncthreads();
    const unsigned s0 = binBase[b], s1 = binBase[b + 1];
    for (unsigned i = s0 + t; i < s1; i += 256) {
        uint2 v = binned[i];
        atomicAdd(&ws[v.x >> 20], __uint_as_float(v.y));
    }
    __syncthreads();
    if (t < BINW) {
        int node = b * BINW + t;
        if (node < n) {
            float d = 1.0f + ws[t];  // self-loop weight 1
            float di = (d > 0.0f) ? (1.0f / sqrtf(fmaxf(d, 1e-12f))) : 0.0f;
            double qv = pk1[node].x;
            pk1[node] = double2{qv, (double)di};
            pk2[node] = double2{cvals[1] + (double)(di * di) * qv, (double)di};
        }
    }
}

// per bin: acc[dlow] += f64(f32(dis_s*ew)) * q_s  (4-deep gather ILP, LDS f64
// atomics); then pk2.x += dis_d * acc. Edge reads coalesced (stride 256).
__global__ __launch_bounds__(256) void spmv1_kernel(
        const uint2* __restrict__ binned, const unsigned* __restrict__ binBase,
        const double2* __restrict__ pk1, double2* __restrict__ pk2, int n) {
    __shared__ double acc[BINW];
    const int b = blockIdx.x;
    const int t = threadIdx.x;
    if (t < BINW) acc[t] = 0.0;
    __syncthreads();
    const unsigned s0 = binBase[b], s1 = binBase[b + 1];
    for (unsigned tile = s0; tile < s1; tile += 1024) {
        uint2 ee[4];
        double2 aa[4];
        bool ok[4];
#pragma unroll
        for (int k = 0; k < 4; k++) {
            unsigned idx = tile + t + k * 256u;
            ok[k] = (idx < s1);
            if (ok[k]) ee[k] = binned[idx];           // coalesced
        }
#pragma unroll
        for (int k = 0; k < 4; k++)
            if (ok[k]) aa[k] = pk1[ee[k].x & 0xFFFFFu];  // 4 scattered L2 gathers
#pragma unroll
        for (int k = 0; k < 4; k++)
            if (ok[k]) {
                float nm = (float)aa[k].y * __uint_as_float(ee[k].y);
                atomicAdd(&acc[ee[k].x >> 20], (double)nm * aa[k].x);
            }
    }
    __syncthreads();
    if (t < BINW) {
        int node = b * BINW + t;
        if (node < n) {
            double2 me = pk2[node];
            pk2[node].x = me.x + me.y * acc[t];
        }
    }
}

// per bin: acc[dlow] += f64(f32(dis_s*ew)) * t_s; u = c0 + dis^2 t + dis*acc;
// out = round(clip(u,0,10))
__global__ __launch_bounds__(256) void spmv2_head_kernel(
        const uint2* __restrict__ binned, const unsigned* __restrict__ binBase,
        const double2* __restrict__ pk2, const double* __restrict__ cvals,
        float* __restrict__ out, int n) {
    __shared__ double acc[BINW];
    const int b = blockIdx.x;
    const int t = threadIdx.x;
    if (t < BINW) acc[t] = 0.0;
    __syncthreads();
    const unsigned s0 = binBase[b], s1 = binBase[b + 1];
    for (unsigned tile = s0; tile < s1; tile += 1024) {
        uint2 ee[4];
        double2 aa[4];
        bool ok[4];
#pragma unroll
        for (int k = 0; k < 4; k++) {
            unsigned idx = tile + t + k * 256u;
            ok[k] = (idx < s1);
            if (ok[k]) ee[k] = binned[idx];
        }
#pragma unroll
        for (int k = 0; k < 4; k++)
            if (ok[k]) aa[k] = pk2[ee[k].x & 0xFFFFFu];  // {t, dis}
#pragma unroll
        for (int k = 0; k < 4; k++)
            if (ok[k]) {
                float nm = (float)aa[k].y * __uint_as_float(ee[k].y);
                atomicAdd(&acc[ee[k].x >> 20], (double)nm * aa[k].x);
            }
    }
    __syncthreads();
    if (t < BINW) {
        int node = b * BINW + t;
        if (node < n) {
            double2 me = pk2[node];
            float di = (float)me.y;
            double u = cvals[0] + (double)(di * di) * me.x + me.y * acc[t];
            float o = (float)u;
            o = fminf(fmaxf(o, 0.0f), 10.0f);
            out[node] = rintf(o);  // v_rndne_f32: half-to-even, matches jnp.round
        }
    }
}

extern "C" void kernel_launch(void* const* d_in, const int* in_sizes, int n_in,
                              void* d_out, int out_size, void* d_ws, size_t ws_size,
                              hipStream_t stream) {
    const float* x   = (const float*)d_in[0];  // [N, 128]
    const int*   eix = (const int*)d_in[1];    // [2, E]
    const float* ew  = (const float*)d_in[2];  // [E]
    const float* W1  = (const float*)d_in[3];  // [128, 64]
    const float* b1  = (const float*)d_in[4];  // [64]
    const float* W2  = (const float*)d_in[5];  // [64, 64]
    const float* b2  = (const float*)d_in[6];  // [64]
    const float* fcw = (const float*)d_in[7];  // [64]
    const float* fcb = (const float*)d_in[8];  // [1]
    float* out = (float*)d_out;                // [N]

    const int n = in_sizes[0] / DIN;
    const int e = in_sizes[2];
    const int* src = eix;
    const int* dst = eix + e;
    const int nb = (n + BINW - 1) / BINW;      // 782 bins at n=100000

    // workspace layout (8-byte units, 512B-aligned regions); ~17 MB
    auto al = [](size_t v) { return (v + 63) & ~(size_t)63; };
    double* ws = (double*)d_ws;
    size_t o = 0;
    double*   w1f    = ws + o; o += al(DIN);
    double*   cvals  = ws + o; o += al(2);
    double2*  pk1    = (double2*)(ws + o); o += al((size_t)n * 2);
    double2*  pk2    = (double2*)(ws + o); o += al((size_t)n * 2);
    unsigned* binCnt = (unsigned*)(ws + o); o += al(((size_t)nb + 1) / 2);
    unsigned* binBase= (unsigned*)(ws + o); o += al(((size_t)nb + 2) / 2);
    unsigned* binCur = (unsigned*)(ws + o); o += al(((size_t)nb + 1) / 2);
    uint2*    binned = (uint2*)(ws + o);   // e * 8B = 12.8 MB

    const int hblk = (e + CHUNK - 1) / CHUNK;        // 196
    const int gemvblk = (n + 3) / 4;                 // 4 rows (waves) per block
    const int zblk = (nb + 255) / 256;

    precompute_kernel<<<1 + zblk, 256, 0, stream>>>(W1, b1, W2, b2, fcw, fcb,
                                                    w1f, cvals, binCnt, nb);
    hist_gemv_kernel<<<hblk + gemvblk, 256, 0, stream>>>(dst, x, w1f, binCnt,
                                                         pk1, n, e, nb, hblk);
    scan_kernel<<<1, 256, 0, stream>>>(binCnt, binBase, binCur, nb);
    binscatter_kernel<<<hblk, 256, 0, stream>>>(src, dst, ew, binCur, binned, e, nb);
    setup_kernel<<<nb, 256, 0, stream>>>(binned, binBase, cvals, pk1, pk2, n);
    spmv1_kernel<<<nb, 256, 0, stream>>>(binned, binBase, pk1, pk2, n);
    spmv2_head_kernel<<<nb, 256, 0, stream>>>(binned, binBase, pk2, cvals, out, n);
}

// Round 6
// 191.422 us; speedup vs baseline: 1.3989x; 1.1169x over previous
//
#include <hip/hip_runtime.h>

#define DIN 128
#define BINW 128        // nodes per bin
#define BINSHIFT 7
#define NB_MAX 1024     // supports n <= 131072
#define CHUNK 8192      // edges per binning block

// ---------------------------------------------------------------------------
// out = round(clip( A^2 (X w1f) + c1*(A 1) + c0 , 0, 10)),  A = D^-1/2 (W+I) D^-1/2
// w2f = W2@fcw, w1f = W1@w2f, c1 = b1·w2f, c0 = b2·fcw + fcb.
//
// Scattered-op cost model v3 (rounds 0-4): per-edge global scattered ATOMICS
// are a ~20 G/s chip-level wall (invariant to padding r2 / per-thread MLP r3).
// Scattered plain READS/WRITES into L2-resident regions pipeline fine.
// Counting-sort build with per-(chunk,bin) bases precomputed by a scan, so
// placement is single-pass, zero global atomics (r4 lesson: binscatter was
// latency-bound at 6.7% occupancy + duplicated histogram work).
//   K1 prep:     w1f, c0, c1
//   K2 hist+gemv: LDS hist of dst>>7 per chunk -> histT[c][b] coalesced
//                (+ gemv q -> pk1.x)
//   K3 binscan:  wave per bin: exscan histT over chunks -> chunkOfsT[c][b];
//                binCnt[b] = total
//   K4 scan:     binBase = exscan(binCnt)
//   K5 binscatter: 1024 thr: sbase[b]=binBase+chunkOfs (coalesced); one pass:
//                p = sbase[b] + ldsAtomic(cnt[b]); binned[p]={src|dlow<<20,ew}
//   K6 setup:    per bin: wsum via LDS f32 atomics -> dis; pk1={q,dis};
//                pk2={c1+dis^2 q, dis}
//   K7 spmv1:    per bin: acc[dlow] += f64(f32(dis_s*ew))*q_s (LDS f64 atomic);
//                pk2.x += dis_d * acc
//   K8 spmv2:    same with pk2 gather; u = c0+dis^2 t+dis*acc; out=round(clip)
// (Round 5 was an MI355X container/infra failure; identical resubmission.)
// ---------------------------------------------------------------------------

__global__ void precompute_kernel(const float* __restrict__ W1, const float* __restrict__ b1,
                                  const float* __restrict__ W2, const float* __restrict__ b2,
                                  const float* __restrict__ fcw, const float* __restrict__ fcb,
                                  double* __restrict__ w1f, double* __restrict__ cvals) {
    const int t = threadIdx.x;
    __shared__ double sw2f[64];
    if (t < 64) {
        double s = 0.0;
        for (int j = 0; j < 64; j++) s += (double)W2[t * 64 + j] * (double)fcw[j];
        sw2f[t] = s;
    }
    __syncthreads();
    if (t < 128) {
        double s = 0.0;
        for (int j = 0; j < 64; j++) s += (double)W1[t * 64 + j] * sw2f[j];
        w1f[t] = s;
    }
    if (t == 128) {
        double c1 = 0.0, c0 = (double)fcb[0];
        for (int j = 0; j < 64; j++) {
            c1 += (double)b1[j] * sw2f[j];
            c0 += (double)b2[j] * (double)fcw[j];
        }
        cvals[0] = c0;
        cvals[1] = c1;
    }
}

// blocks [0,hblk): LDS histogram of CHUNK edges -> histT[c][b] (coalesced
// plain stores, no global atomics). blocks [hblk,..): gemv q -> pk1[row].x
__global__ __launch_bounds__(256) void hist_gemv_kernel(
        const int* __restrict__ dst, const float* __restrict__ X,
        const double* __restrict__ w1f, unsigned* __restrict__ histT,
        double2* __restrict__ pk1, int n, int e, int nb, int hblk) {
    __shared__ unsigned cnt[NB_MAX];
    const int blk = blockIdx.x;
    const int t = threadIdx.x;
    if (blk < hblk) {
        for (int b = t; b < nb; b += 256) cnt[b] = 0u;
        __syncthreads();
        const long base = (long)blk * CHUNK;
        for (int k = 0; k < CHUNK / 256; k++) {
            long i = base + k * 256 + t;
            if (i < e) atomicAdd(&cnt[dst[i] >> BINSHIFT], 1u);
        }
        __syncthreads();
        for (int b = t; b < nb; b += 256)
            histT[(long)blk * nb + b] = cnt[b];          // coalesced
        return;
    }
    long g = (long)(blk - hblk) * 256 + t;
    int row = (int)(g >> 6);
    int lane = (int)(g & 63);
    if (row >= n) return;
    float2 x = *(const float2*)(X + (long)row * DIN + 2 * lane);  // coalesced
    double v = (double)x.x * w1f[2 * lane] + (double)x.y * w1f[2 * lane + 1];
#pragma unroll
    for (int off = 32; off > 0; off >>= 1) v += __shfl_down(v, off, 64);
    if (lane == 0) pk1[row].x = v;
}

// one wave per bin: exclusive scan of histT[c][b] over chunks c ->
// chunkOfsT[c][b]; binCnt[b] = bin total. Scattered 4B ops, 613KB L2 region.
__global__ __launch_bounds__(256) void binscan_kernel(
        const unsigned* __restrict__ histT, unsigned* __restrict__ chunkOfsT,
        unsigned* __restrict__ binCnt, int nb, int hblk) {
    int gw = (int)((blockIdx.x * 256 + threadIdx.x) >> 6);  // wave = bin
    int l = threadIdx.x & 63;
    if (gw >= nb) return;
    unsigned carry = 0u;
    for (int c0 = 0; c0 < hblk; c0 += 64) {
        int c = c0 + l;
        unsigned v = (c < hblk) ? histT[(long)c * nb + gw] : 0u;
        unsigned s = v;
#pragma unroll
        for (int off = 1; off < 64; off <<= 1) {
            unsigned u = __shfl_up(s, off, 64);
            if (l >= off) s += u;
        }
        if (c < hblk) chunkOfsT[(long)c * nb + gw] = carry + s - v;
        carry += (unsigned)__shfl((int)s, 63, 64);
    }
    if (l == 0) binCnt[gw] = carry;
}

// 1 block: exclusive scan of binCnt[nb] -> binBase[nb+1]
__global__ void scan_kernel(const unsigned* __restrict__ binCnt,
                            unsigned* __restrict__ binBase, int nb) {
    __shared__ unsigned part[256];
    const int t = threadIdx.x;
    unsigned loc[4];
    unsigned s = 0;
#pragma unroll
    for (int k = 0; k < 4; k++) {
        int idx = t * 4 + k;
        unsigned v = (idx < nb) ? binCnt[idx] : 0u;
        loc[k] = s;
        s += v;
    }
    part[t] = s;
    __syncthreads();
    if (t == 0) {
        unsigned run = 0;
        for (int j = 0; j < 256; j++) { unsigned v = part[j]; part[j] = run; run += v; }
    }
    __syncthreads();
    unsigned p = part[t];
#pragma unroll
    for (int k = 0; k < 4; k++) {
        int idx = t * 4 + k;
        if (idx < nb) binBase[idx] = p + loc[k];
    }
    if (t == 255) binBase[nb] = p + s;
}

// single-pass placement, zero global atomics: sbase from binBase+chunkOfsT
// (coalesced), local order via LDS atomic, scattered 8B store (run-local
// frontier ~84B/bin). 1024 thr x 196 blocks = 12 waves/CU.
__global__ __launch_bounds__(1024) void binscatter_kernel(
        const int* __restrict__ src, const int* __restrict__ dst,
        const float* __restrict__ ew, const unsigned* __restrict__ binBase,
        const unsigned* __restrict__ chunkOfsT,
        uint2* __restrict__ binned, int e, int nb) {
    __shared__ unsigned cnt[NB_MAX];
    __shared__ unsigned sbase[NB_MAX];
    const int c = blockIdx.x;
    const int t = threadIdx.x;
    for (int b = t; b < nb; b += 1024) {
        cnt[b] = 0u;
        sbase[b] = binBase[b] + chunkOfsT[(long)c * nb + b];  // coalesced
    }
    __syncthreads();
    const long base = (long)c * CHUNK;
#pragma unroll
    for (int k = 0; k < CHUNK / 1024; k++) {
        long i = base + k * 1024 + t;
        if (i < e) {
            int d = dst[i];
            int b = d >> BINSHIFT;
            unsigned p = sbase[b] + atomicAdd(&cnt[b], 1u);
            binned[p] = uint2{(unsigned)src[i] | ((unsigned)(d & (BINW - 1)) << 20),
                              __float_as_uint(ew[i])};
        }
    }
}

// per bin: wsum[dlow] += ew (LDS f32 atomics, coalesced edge reads) -> dis;
// pk1={q,dis}; pk2={c1+dis^2 q, dis}
__global__ __launch_bounds__(256) void setup_kernel(
        const uint2* __restrict__ binned, const unsigned* __restrict__ binBase,
        const double* __restrict__ cvals,
        double2* __restrict__ pk1, double2* __restrict__ pk2, int n) {
    __shared__ float ws[BINW];
    const int b = blockIdx.x;
    const int t = threadIdx.x;
    if (t < BINW) ws[t] = 0.0f;
    __syncthreads();
    const unsigned s0 = binBase[b], s1 = binBase[b + 1];
    for (unsigned i = s0 + t; i < s1; i += 256) {
        uint2 v = binned[i];
        atomicAdd(&ws[v.x >> 20], __uint_as_float(v.y));
    }
    __syncthreads();
    if (t < BINW) {
        int node = b * BINW + t;
        if (node < n) {
            float d = 1.0f + ws[t];  // self-loop weight 1
            float di = (d > 0.0f) ? (1.0f / sqrtf(fmaxf(d, 1e-12f))) : 0.0f;
            double qv = pk1[node].x;
            pk1[node] = double2{qv, (double)di};
            pk2[node] = double2{cvals[1] + (double)(di * di) * qv, (double)di};
        }
    }
}

// per bin: acc[dlow] += f64(f32(dis_s*ew)) * q_s  (4-deep gather ILP, LDS f64
// atomics); then pk2.x += dis_d * acc. Edge reads coalesced.
__global__ __launch_bounds__(256) void spmv1_kernel(
        const uint2* __restrict__ binned, const unsigned* __restrict__ binBase,
        const double2* __restrict__ pk1, double2* __restrict__ pk2, int n) {
    __shared__ double acc[BINW];
    const int b = blockIdx.x;
    const int t = threadIdx.x;
    if (t < BINW) acc[t] = 0.0;
    __syncthreads();
    const unsigned s0 = binBase[b], s1 = binBase[b + 1];
    for (unsigned tile = s0; tile < s1; tile += 1024) {
        uint2 ee[4];
        double2 aa[4];
        bool ok[4];
#pragma unroll
        for (int k = 0; k < 4; k++) {
            unsigned idx = tile + t + k * 256u;
            ok[k] = (idx < s1);
            if (ok[k]) ee[k] = binned[idx];           // coalesced
        }
#pragma unroll
        for (int k = 0; k < 4; k++)
            if (ok[k]) aa[k] = pk1[ee[k].x & 0xFFFFFu];  // 4 scattered L2 gathers
#pragma unroll
        for (int k = 0; k < 4; k++)
            if (ok[k]) {
                float nm = (float)aa[k].y * __uint_as_float(ee[k].y);
                atomicAdd(&acc[ee[k].x >> 20], (double)nm * aa[k].x);
            }
    }
    __syncthreads();
    if (t < BINW) {
        int node = b * BINW + t;
        if (node < n) {
            double2 me = pk2[node];
            pk2[node].x = me.x + me.y * acc[t];
        }
    }
}

// per bin: acc[dlow] += f64(f32(dis_s*ew)) * t_s; u = c0 + dis^2 t + dis*acc;
// out = round(clip(u,0,10))
__global__ __launch_bounds__(256) void spmv2_head_kernel(
        const uint2* __restrict__ binned, const unsigned* __restrict__ binBase,
        const double2* __restrict__ pk2, const double* __restrict__ cvals,
        float* __restrict__ out, int n) {
    __shared__ double acc[BINW];
    const int b = blockIdx.x;
    const int t = threadIdx.x;
    if (t < BINW) acc[t] = 0.0;
    __syncthreads();
    const unsigned s0 = binBase[b], s1 = binBase[b + 1];
    for (unsigned tile = s0; tile < s1; tile += 1024) {
        uint2 ee[4];
        double2 aa[4];
        bool ok[4];
#pragma unroll
        for (int k = 0; k < 4; k++) {
            unsigned idx = tile + t + k * 256u;
            ok[k] = (idx < s1);
            if (ok[k]) ee[k] = binned[idx];
        }
#pragma unroll
        for (int k = 0; k < 4; k++)
            if (ok[k]) aa[k] = pk2[ee[k].x & 0xFFFFFu];  // {t, dis}
#pragma unroll
        for (int k = 0; k < 4; k++)
            if (ok[k]) {
                float nm = (float)aa[k].y * __uint_as_float(ee[k].y);
                atomicAdd(&acc[ee[k].x >> 20], (double)nm * aa[k].x);
            }
    }
    __syncthreads();
    if (t < BINW) {
        int node = b * BINW + t;
        if (node < n) {
            double2 me = pk2[node];
            float di = (float)me.y;
            double u = cvals[0] + (double)(di * di) * me.x + me.y * acc[t];
            float o = (float)u;
            o = fminf(fmaxf(o, 0.0f), 10.0f);
            out[node] = rintf(o);  // v_rndne_f32: half-to-even, matches jnp.round
        }
    }
}

extern "C" void kernel_launch(void* const* d_in, const int* in_sizes, int n_in,
                              void* d_out, int out_size, void* d_ws, size_t ws_size,
                              hipStream_t stream) {
    const float* x   = (const float*)d_in[0];  // [N, 128]
    const int*   eix = (const int*)d_in[1];    // [2, E]
    const float* ew  = (const float*)d_in[2];  // [E]
    const float* W1  = (const float*)d_in[3];  // [128, 64]
    const float* b1  = (const float*)d_in[4];  // [64]
    const float* W2  = (const float*)d_in[5];  // [64, 64]
    const float* b2  = (const float*)d_in[6];  // [64]
    const float* fcw = (const float*)d_in[7];  // [64]
    const float* fcb = (const float*)d_in[8];  // [1]
    float* out = (float*)d_out;                // [N]

    const int n = in_sizes[0] / DIN;
    const int e = in_sizes[2];
    const int* src = eix;
    const int* dst = eix + e;
    const int nb = (n + BINW - 1) / BINW;            // 782 bins at n=100000
    const int hblk = (e + CHUNK - 1) / CHUNK;        // 196 chunks

    // workspace layout (8-byte units, 64-unit aligned regions); ~19 MB
    auto al = [](size_t v) { return (v + 63) & ~(size_t)63; };
    double* ws = (double*)d_ws;
    size_t o = 0;
    double*   w1f     = ws + o; o += al(DIN);
    double*   cvals   = ws + o; o += al(2);
    double2*  pk1     = (double2*)(ws + o); o += al((size_t)n * 2);
    double2*  pk2     = (double2*)(ws + o); o += al((size_t)n * 2);
    unsigned* binCnt  = (unsigned*)(ws + o); o += al(((size_t)nb + 1) / 2);
    unsigned* binBase = (unsigned*)(ws + o); o += al(((size_t)nb + 2) / 2);
    unsigned* histT   = (unsigned*)(ws + o); o += al(((size_t)nb * hblk + 1) / 2);
    unsigned* chunkOfsT = (unsigned*)(ws + o); o += al(((size_t)nb * hblk + 1) / 2);
    uint2*    binned  = (uint2*)(ws + o);   // e * 8B = 12.8 MB

    const int gemvblk = (n + 3) / 4;                 // 4 rows (waves) per block
    const int bsblk = (nb * 64 + 255) / 256;         // binscan: wave per bin

    precompute_kernel<<<1, 256, 0, stream>>>(W1, b1, W2, b2, fcw, fcb, w1f, cvals);
    hist_gemv_kernel<<<hblk + gemvblk, 256, 0, stream>>>(dst, x, w1f, histT,
                                                         pk1, n, e, nb, hblk);
    binscan_kernel<<<bsblk, 256, 0, stream>>>(histT, chunkOfsT, binCnt, nb, hblk);
    scan_kernel<<<1, 256, 0, stream>>>(binCnt, binBase, nb);
    binscatter_kernel<<<hblk, 1024, 0, stream>>>(src, dst, ew, binBase, chunkOfsT,
                                                 binned, e, nb);
    setup_kernel<<<nb, 256, 0, stream>>>(binned, binBase, cvals, pk1, pk2, n);
    spmv1_kernel<<<nb, 256, 0, stream>>>(binned, binBase, pk1, pk2, n);
    spmv2_head_kernel<<<nb, 256, 0, stream>>>(binned, binBase, pk2, cvals, out, n);
}

// Round 7
// 191.123 us; speedup vs baseline: 1.4011x; 1.0016x over previous
//
#include <hip/hip_runtime.h>

#define DIN 128
#define BINW 128        // nodes per bin
#define BINSHIFT 7
#define NB_MAX 1024     // supports n <= 131072
#define CHUNK 8192      // edges per binning block

// ---------------------------------------------------------------------------
// out = round(clip( A^2 q + c1*(A 1) + c0 , 0, 10)),  A = D^-1/2 (W+I) D^-1/2
// q = X w1f; w2f = W2@fcw, w1f = W1@w2f, c1 = b1·w2f, c0 = b2·fcw + fcb.
// Factored:  t = A q + c1·1 ;  u = A t + c0.
// Per-node:  t_i = c1 + dis_i^2 q_i + dis_i * sum_e ew_e * (dis_s q_s)
//            u_i = c0 + dis_i * ( dis_i t_i + sum_e ew_e * (dis_s t_s) )
// => gather tables are PREMULTIPLIED 8B f64: v1 = dis*q, v2 = dis*t.
//    Per edge: 1 coalesced 8B read + 1 scattered 8B gather + 1 f64 FMA (LDS).
//
// Scattered-op cost model v3 (rounds 0-6): per-edge global scattered ATOMICS
// ~20 G/s chip wall (invariant to padding r2, per-thread MLP r3). Scattered
// plain reads/writes to L2-resident regions pipeline at ~35-45 G/s. Build
// adjacency via counting sort: all global atomics are per-(chunk,bin).
//   K1 prep:      w1f, c0, c1
//   K2 hist+gemv: LDS hist of dst>>7 per chunk -> histT[c][b] (+ q = X w1f)
//   K3 binscan:   wave/bin exscan histT over chunks -> chunkOfsT; binCnt
//   K4 scan:      binBase = exscan(binCnt)
//   K5 binscatter: single-pass placement, zero global atomics
//   K6 setup:     per bin: wsum (LDS f32) -> dis; v1=dis*q; tpart=c1+dis^2 q
//   K7 spmv1:     acc[dlow] += ew * v1[s] (8-deep ILP); v2=dis*(tpart+dis*acc)
//   K8 spmv2:     acc[dlow] += ew * v2[s]; u=c0+dis*(v2+acc); out=round(clip)
// ---------------------------------------------------------------------------

__global__ void precompute_kernel(const float* __restrict__ W1, const float* __restrict__ b1,
                                  const float* __restrict__ W2, const float* __restrict__ b2,
                                  const float* __restrict__ fcw, const float* __restrict__ fcb,
                                  double* __restrict__ w1f, double* __restrict__ cvals) {
    const int t = threadIdx.x;
    __shared__ double sw2f[64];
    if (t < 64) {
        double s = 0.0;
        for (int j = 0; j < 64; j++) s += (double)W2[t * 64 + j] * (double)fcw[j];
        sw2f[t] = s;
    }
    __syncthreads();
    if (t < 128) {
        double s = 0.0;
        for (int j = 0; j < 64; j++) s += (double)W1[t * 64 + j] * sw2f[j];
        w1f[t] = s;
    }
    if (t == 128) {
        double c1 = 0.0, c0 = (double)fcb[0];
        for (int j = 0; j < 64; j++) {
            c1 += (double)b1[j] * sw2f[j];
            c0 += (double)b2[j] * (double)fcw[j];
        }
        cvals[0] = c0;
        cvals[1] = c1;
    }
}

// blocks [0,hblk): LDS histogram of CHUNK edges -> histT[c][b] (coalesced
// plain stores, no global atomics). blocks [hblk,..): gemv q[row] = X w1f
__global__ __launch_bounds__(256) void hist_gemv_kernel(
        const int* __restrict__ dst, const float* __restrict__ X,
        const double* __restrict__ w1f, unsigned* __restrict__ histT,
        double* __restrict__ q, int n, int e, int nb, int hblk) {
    __shared__ unsigned cnt[NB_MAX];
    const int blk = blockIdx.x;
    const int t = threadIdx.x;
    if (blk < hblk) {
        for (int b = t; b < nb; b += 256) cnt[b] = 0u;
        __syncthreads();
        const long base = (long)blk * CHUNK;
        for (int k = 0; k < CHUNK / 256; k++) {
            long i = base + k * 256 + t;
            if (i < e) atomicAdd(&cnt[dst[i] >> BINSHIFT], 1u);
        }
        __syncthreads();
        for (int b = t; b < nb; b += 256)
            histT[(long)blk * nb + b] = cnt[b];          // coalesced
        return;
    }
    long g = (long)(blk - hblk) * 256 + t;
    int row = (int)(g >> 6);
    int lane = (int)(g & 63);
    if (row >= n) return;
    float2 x = *(const float2*)(X + (long)row * DIN + 2 * lane);  // coalesced
    double v = (double)x.x * w1f[2 * lane] + (double)x.y * w1f[2 * lane + 1];
#pragma unroll
    for (int off = 32; off > 0; off >>= 1) v += __shfl_down(v, off, 64);
    if (lane == 0) q[row] = v;
}

// one wave per bin: exclusive scan of histT[c][b] over chunks c ->
// chunkOfsT[c][b]; binCnt[b] = bin total. Scattered 4B ops, 613KB L2 region.
__global__ __launch_bounds__(256) void binscan_kernel(
        const unsigned* __restrict__ histT, unsigned* __restrict__ chunkOfsT,
        unsigned* __restrict__ binCnt, int nb, int hblk) {
    int gw = (int)((blockIdx.x * 256 + threadIdx.x) >> 6);  // wave = bin
    int l = threadIdx.x & 63;
    if (gw >= nb) return;
    unsigned carry = 0u;
    for (int c0 = 0; c0 < hblk; c0 += 64) {
        int c = c0 + l;
        unsigned v = (c < hblk) ? histT[(long)c * nb + gw] : 0u;
        unsigned s = v;
#pragma unroll
        for (int off = 1; off < 64; off <<= 1) {
            unsigned u = __shfl_up(s, off, 64);
            if (l >= off) s += u;
        }
        if (c < hblk) chunkOfsT[(long)c * nb + gw] = carry + s - v;
        carry += (unsigned)__shfl((int)s, 63, 64);
    }
    if (l == 0) binCnt[gw] = carry;
}

// 1 block: exclusive scan of binCnt[nb] -> binBase[nb+1]
__global__ void scan_kernel(const unsigned* __restrict__ binCnt,
                            unsigned* __restrict__ binBase, int nb) {
    __shared__ unsigned part[256];
    const int t = threadIdx.x;
    unsigned loc[4];
    unsigned s = 0;
#pragma unroll
    for (int k = 0; k < 4; k++) {
        int idx = t * 4 + k;
        unsigned v = (idx < nb) ? binCnt[idx] : 0u;
        loc[k] = s;
        s += v;
    }
    part[t] = s;
    __syncthreads();
    if (t == 0) {
        unsigned run = 0;
        for (int j = 0; j < 256; j++) { unsigned v = part[j]; part[j] = run; run += v; }
    }
    __syncthreads();
    unsigned p = part[t];
#pragma unroll
    for (int k = 0; k < 4; k++) {
        int idx = t * 4 + k;
        if (idx < nb) binBase[idx] = p + loc[k];
    }
    if (t == 255) binBase[nb] = p + s;
}

// single-pass placement, zero global atomics: sbase from binBase+chunkOfsT
// (coalesced), local order via LDS atomic, scattered 8B store (run-local
// frontier ~84B/bin). 1024 thr x 196 blocks = 12 waves/CU.
__global__ __launch_bounds__(1024) void binscatter_kernel(
        const int* __restrict__ src, const int* __restrict__ dst,
        const float* __restrict__ ew, const unsigned* __restrict__ binBase,
        const unsigned* __restrict__ chunkOfsT,
        uint2* __restrict__ binned, int e, int nb) {
    __shared__ unsigned cnt[NB_MAX];
    __shared__ unsigned sbase[NB_MAX];
    const int c = blockIdx.x;
    const int t = threadIdx.x;
    for (int b = t; b < nb; b += 1024) {
        cnt[b] = 0u;
        sbase[b] = binBase[b] + chunkOfsT[(long)c * nb + b];  // coalesced
    }
    __syncthreads();
    const long base = (long)c * CHUNK;
#pragma unroll
    for (int k = 0; k < CHUNK / 1024; k++) {
        long i = base + k * 1024 + t;
        if (i < e) {
            int d = dst[i];
            int b = d >> BINSHIFT;
            unsigned p = sbase[b] + atomicAdd(&cnt[b], 1u);
            binned[p] = uint2{(unsigned)src[i] | ((unsigned)(d & (BINW - 1)) << 20),
                              __float_as_uint(ew[i])};
        }
    }
}

// per bin: wsum[dlow] += ew (LDS f32 atomics) -> dis; disA = dis;
// v1 = dis*q; tpart = c1 + dis^2 q
__global__ __launch_bounds__(256) void setup_kernel(
        const uint2* __restrict__ binned, const unsigned* __restrict__ binBase,
        const double* __restrict__ cvals, const double* __restrict__ q,
        float* __restrict__ disA, double* __restrict__ v1,
        double* __restrict__ tpart, int n) {
    __shared__ float ws[BINW];
    const int b = blockIdx.x;
    const int t = threadIdx.x;
    if (t < BINW) ws[t] = 0.0f;
    __syncthreads();
    const unsigned s0 = binBase[b], s1 = binBase[b + 1];
    for (unsigned i = s0 + t; i < s1; i += 256) {
        uint2 v = binned[i];
        atomicAdd(&ws[v.x >> 20], __uint_as_float(v.y));
    }
    __syncthreads();
    if (t < BINW) {
        int node = b * BINW + t;
        if (node < n) {
            float d = 1.0f + ws[t];  // self-loop weight 1
            float di = (d > 0.0f) ? (1.0f / sqrtf(fmaxf(d, 1e-12f))) : 0.0f;
            double qv = q[node];
            disA[node] = di;
            v1[node] = (double)di * qv;
            tpart[node] = cvals[1] + (double)(di * di) * qv;
        }
    }
}

// per bin: acc[dlow] += ew * v1[s]  (8-deep gather ILP, 8B gathers, LDS f64
// atomics); epilogue: t = tpart + dis*acc; v2 = dis*t.
__global__ __launch_bounds__(256) void spmv1_kernel(
        const uint2* __restrict__ binned, const unsigned* __restrict__ binBase,
        const double* __restrict__ v1, const float* __restrict__ disA,
        const double* __restrict__ tpart, double* __restrict__ v2, int n) {
    __shared__ double acc[BINW];
    const int b = blockIdx.x;
    const int t = threadIdx.x;
    if (t < BINW) acc[t] = 0.0;
    __syncthreads();
    const unsigned s0 = binBase[b], s1 = binBase[b + 1];
    for (unsigned tile = s0; tile < s1; tile += 2048) {
        uint2 ee[8];
        double vv[8];
        bool ok[8];
#pragma unroll
        for (int k = 0; k < 8; k++) {
            unsigned idx = tile + t + k * 256u;
            ok[k] = (idx < s1);
            if (ok[k]) ee[k] = binned[idx];             // coalesced 8B
        }
#pragma unroll
        for (int k = 0; k < 8; k++)
            if (ok[k]) vv[k] = v1[ee[k].x & 0xFFFFFu];  // scattered 8B gather
#pragma unroll
        for (int k = 0; k < 8; k++)
            if (ok[k])
                atomicAdd(&acc[ee[k].x >> 20],
                          (double)__uint_as_float(ee[k].y) * vv[k]);
    }
    __syncthreads();
    if (t < BINW) {
        int node = b * BINW + t;
        if (node < n) {
            double di = (double)disA[node];
            double tv = tpart[node] + di * acc[t];
            v2[node] = di * tv;
        }
    }
}

// per bin: acc[dlow] += ew * v2[s]; u = c0 + dis*(v2 + acc); out=round(clip)
__global__ __launch_bounds__(256) void spmv2_head_kernel(
        const uint2* __restrict__ binned, const unsigned* __restrict__ binBase,
        const double* __restrict__ v2, const float* __restrict__ disA,
        const double* __restrict__ cvals, float* __restrict__ out, int n) {
    __shared__ double acc[BINW];
    const int b = blockIdx.x;
    const int t = threadIdx.x;
    if (t < BINW) acc[t] = 0.0;
    __syncthreads();
    const unsigned s0 = binBase[b], s1 = binBase[b + 1];
    for (unsigned tile = s0; tile < s1; tile += 2048) {
        uint2 ee[8];
        double vv[8];
        bool ok[8];
#pragma unroll
        for (int k = 0; k < 8; k++) {
            unsigned idx = tile + t + k * 256u;
            ok[k] = (idx < s1);
            if (ok[k]) ee[k] = binned[idx];
        }
#pragma unroll
        for (int k = 0; k < 8; k++)
            if (ok[k]) vv[k] = v2[ee[k].x & 0xFFFFFu];
#pragma unroll
        for (int k = 0; k < 8; k++)
            if (ok[k])
                atomicAdd(&acc[ee[k].x >> 20],
                          (double)__uint_as_float(ee[k].y) * vv[k]);
    }
    __syncthreads();
    if (t < BINW) {
        int node = b * BINW + t;
        if (node < n) {
            double u = cvals[0] + (double)disA[node] * (v2[node] + acc[t]);
            float o = (float)u;
            o = fminf(fmaxf(o, 0.0f), 10.0f);
            out[node] = rintf(o);  // v_rndne_f32: half-to-even, matches jnp.round
        }
    }
}

extern "C" void kernel_launch(void* const* d_in, const int* in_sizes, int n_in,
                              void* d_out, int out_size, void* d_ws, size_t ws_size,
                              hipStream_t stream) {
    const float* x   = (const float*)d_in[0];  // [N, 128]
    const int*   eix = (const int*)d_in[1];    // [2, E]
    const float* ew  = (const float*)d_in[2];  // [E]
    const float* W1  = (const float*)d_in[3];  // [128, 64]
    const float* b1  = (const float*)d_in[4];  // [64]
    const float* W2  = (const float*)d_in[5];  // [64, 64]
    const float* b2  = (const float*)d_in[6];  // [64]
    const float* fcw = (const float*)d_in[7];  // [64]
    const float* fcb = (const float*)d_in[8];  // [1]
    float* out = (float*)d_out;                // [N]

    const int n = in_sizes[0] / DIN;
    const int e = in_sizes[2];
    const int* src = eix;
    const int* dst = eix + e;
    const int nb = (n + BINW - 1) / BINW;            // 782 bins at n=100000
    const int hblk = (e + CHUNK - 1) / CHUNK;        // 196 chunks

    // workspace layout (8-byte units, 64-unit aligned regions); ~18 MB
    auto al = [](size_t v) { return (v + 63) & ~(size_t)63; };
    double* ws = (double*)d_ws;
    size_t o = 0;
    double*   w1f     = ws + o; o += al(DIN);
    double*   cvals   = ws + o; o += al(2);
    double*   q       = ws + o; o += al((size_t)n);
    double*   tpart   = ws + o; o += al((size_t)n);
    double*   v1      = ws + o; o += al((size_t)n);
    double*   v2      = ws + o; o += al((size_t)n);
    float*    disA    = (float*)(ws + o);    o += al(((size_t)n + 1) / 2);
    unsigned* binCnt  = (unsigned*)(ws + o); o += al(((size_t)nb + 1) / 2);
    unsigned* binBase = (unsigned*)(ws + o); o += al(((size_t)nb + 2) / 2);
    unsigned* histT   = (unsigned*)(ws + o); o += al(((size_t)nb * hblk + 1) / 2);
    unsigned* chunkOfsT = (unsigned*)(ws + o); o += al(((size_t)nb * hblk + 1) / 2);
    uint2*    binned  = (uint2*)(ws + o);   // e * 8B = 12.8 MB

    const int gemvblk = (n + 3) / 4;                 // 4 rows (waves) per block
    const int bsblk = (nb * 64 + 255) / 256;         // binscan: wave per bin

    precompute_kernel<<<1, 256, 0, stream>>>(W1, b1, W2, b2, fcw, fcb, w1f, cvals);
    hist_gemv_kernel<<<hblk + gemvblk, 256, 0, stream>>>(dst, x, w1f, histT,
                                                         q, n, e, nb, hblk);
    binscan_kernel<<<bsblk, 256, 0, stream>>>(histT, chunkOfsT, binCnt, nb, hblk);
    scan_kernel<<<1, 256, 0, stream>>>(binCnt, binBase, nb);
    binscatter_kernel<<<hblk, 1024, 0, stream>>>(src, dst, ew, binBase, chunkOfsT,
                                                 binned, e, nb);
    setup_kernel<<<nb, 256, 0, stream>>>(binned, binBase, cvals, q, disA, v1,
                                         tpart, n);
    spmv1_kernel<<<nb, 256, 0, stream>>>(binned, binBase, v1, disA, tpart, v2, n);
    spmv2_head_kernel<<<nb, 256, 0, stream>>>(binned, binBase, v2, disA, cvals,
                                              out, n);
}

// Round 9
// 173.783 us; speedup vs baseline: 1.5409x; 1.0998x over previous
//
#include <hip/hip_runtime.h>

#define DIN 128
#define BINW 128        // nodes per bin
#define BINSHIFT 7
#define NB_MAX 1024     // supports n <= 131072
#define CHUNK 8192      // edges per binning block

// ---------------------------------------------------------------------------
// out = round(clip( A^2 q + c1*(A 1) + c0 , 0, 10)),  A = D^-1/2 (W+I) D^-1/2
// q = X w1f; w2f = W2@fcw, w1f = W1@w2f, c1 = b1·w2f, c0 = b2·fcw + fcb.
// Factored:  t = A q + c1·1 ;  u = A t + c0.   v1 = dis*q, v2 = dis*t (8B f64).
//
// Scattered-op cost model v4 (rounds 0-7): per-edge global scattered ATOMICS
// ~20 G/s chip wall (invariant to padding r2, per-thread MLP r3). Scattered
// plain reads: TRANSACTION-count-bound (r7: width 16->8B + ILP 4->8 = null).
// This round tests the last lever: WAVE-level parallelism (12 -> 24 waves/CU
// in spmv via 512-thr blocks, 4 LDS sub-accumulators, block-local combine).
//   K1 prep:      w1f, c0, c1
//   K2 hist+gemv: LDS hist of dst>>7 per chunk -> histT (int4 loads)
//                 (+ q = X w1f, float4: 2 rows/wave)
//   K3 binscan:   wave/bin exscan histT over chunks -> chunkOfsT; binCnt
//   K4 scan:      binBase = exscan(binCnt)
//   K5 binscatter: single-pass placement, zero global atomics (int4 loads)
//   K6 setup:     per bin: wsum (LDS f32) -> dis; v1=dis*q; tpart=c1+dis^2 q
//   K7 spmv1:     512 thr: acc[sub][dlow] += ew*v1[s]; v2=dis*(tpart+dis*sum)
//   K8 spmv2:     same with v2 gather; u=c0+dis*(v2+sum); out=round(clip)
// (Round 8 was an MI355X container/infra failure; identical resubmission.)
// ---------------------------------------------------------------------------

__global__ void precompute_kernel(const float* __restrict__ W1, const float* __restrict__ b1,
                                  const float* __restrict__ W2, const float* __restrict__ b2,
                                  const float* __restrict__ fcw, const float* __restrict__ fcb,
                                  double* __restrict__ w1f, double* __restrict__ cvals) {
    const int t = threadIdx.x;
    __shared__ double sw2f[64];
    if (t < 64) {
        double s = 0.0;
        for (int j = 0; j < 64; j++) s += (double)W2[t * 64 + j] * (double)fcw[j];
        sw2f[t] = s;
    }
    __syncthreads();
    if (t < 128) {
        double s = 0.0;
        for (int j = 0; j < 64; j++) s += (double)W1[t * 64 + j] * sw2f[j];
        w1f[t] = s;
    }
    if (t == 128) {
        double c1 = 0.0, c0 = (double)fcb[0];
        for (int j = 0; j < 64; j++) {
            c1 += (double)b1[j] * sw2f[j];
            c0 += (double)b2[j] * (double)fcw[j];
        }
        cvals[0] = c0;
        cvals[1] = c1;
    }
}

// blocks [0,hblk): LDS histogram of CHUNK edges (int4 loads) -> histT[c][b].
// blocks [hblk,..): gemv q = X w1f, float4 loads, 2 rows per 64-lane wave.
__global__ __launch_bounds__(256) void hist_gemv_kernel(
        const int* __restrict__ dst, const float* __restrict__ X,
        const double* __restrict__ w1f, unsigned* __restrict__ histT,
        double* __restrict__ q, int n, int e, int nb, int hblk) {
    __shared__ unsigned cnt[NB_MAX];
    const int blk = blockIdx.x;
    const int t = threadIdx.x;
    if (blk < hblk) {
        for (int b = t; b < nb; b += 256) cnt[b] = 0u;
        __syncthreads();
        const long base = (long)blk * CHUNK;
#pragma unroll
        for (int k = 0; k < CHUNK / 1024; k++) {           // 8 iters of int4
            long i = base + ((long)k * 256 + t) * 4;
            if (i + 3 < e) {
                int4 d4 = *(const int4*)(dst + i);
                atomicAdd(&cnt[d4.x >> BINSHIFT], 1u);
                atomicAdd(&cnt[d4.y >> BINSHIFT], 1u);
                atomicAdd(&cnt[d4.z >> BINSHIFT], 1u);
                atomicAdd(&cnt[d4.w >> BINSHIFT], 1u);
            } else {
                for (int j = 0; j < 4; j++)
                    if (i + j < e) atomicAdd(&cnt[dst[i + j] >> BINSHIFT], 1u);
            }
        }
        __syncthreads();
        for (int b = t; b < nb; b += 256)
            histT[(long)blk * nb + b] = cnt[b];            // coalesced
        return;
    }
    long g = (long)(blk - hblk) * 256 + t;
    int w = (int)(g >> 6);         // global wave index
    int lane = (int)(g & 63);
    int sub = lane >> 5;           // 2 rows per wave
    int l = lane & 31;
    int row = w * 2 + sub;
    if (row >= n) return;
    float4 x = *(const float4*)(X + (long)row * DIN + 4 * l);  // 1KB/wave coalesced
    double v = (double)x.x * w1f[4 * l] + (double)x.y * w1f[4 * l + 1]
             + (double)x.z * w1f[4 * l + 2] + (double)x.w * w1f[4 * l + 3];
#pragma unroll
    for (int off = 16; off > 0; off >>= 1) v += __shfl_down(v, off, 64);
    if (l == 0) q[row] = v;
}

// one wave per bin: exclusive scan of histT[c][b] over chunks c ->
// chunkOfsT[c][b]; binCnt[b] = bin total. Scattered 4B ops, 613KB L2 region.
__global__ __launch_bounds__(256) void binscan_kernel(
        const unsigned* __restrict__ histT, unsigned* __restrict__ chunkOfsT,
        unsigned* __restrict__ binCnt, int nb, int hblk) {
    int gw = (int)((blockIdx.x * 256 + threadIdx.x) >> 6);  // wave = bin
    int l = threadIdx.x & 63;
    if (gw >= nb) return;
    unsigned carry = 0u;
    for (int c0 = 0; c0 < hblk; c0 += 64) {
        int c = c0 + l;
        unsigned v = (c < hblk) ? histT[(long)c * nb + gw] : 0u;
        unsigned s = v;
#pragma unroll
        for (int off = 1; off < 64; off <<= 1) {
            unsigned u = __shfl_up(s, off, 64);
            if (l >= off) s += u;
        }
        if (c < hblk) chunkOfsT[(long)c * nb + gw] = carry + s - v;
        carry += (unsigned)__shfl((int)s, 63, 64);
    }
    if (l == 0) binCnt[gw] = carry;
}

// 1 block: exclusive scan of binCnt[nb] -> binBase[nb+1]
__global__ void scan_kernel(const unsigned* __restrict__ binCnt,
                            unsigned* __restrict__ binBase, int nb) {
    __shared__ unsigned part[256];
    const int t = threadIdx.x;
    unsigned loc[4];
    unsigned s = 0;
#pragma unroll
    for (int k = 0; k < 4; k++) {
        int idx = t * 4 + k;
        unsigned v = (idx < nb) ? binCnt[idx] : 0u;
        loc[k] = s;
        s += v;
    }
    part[t] = s;
    __syncthreads();
    if (t == 0) {
        unsigned run = 0;
        for (int j = 0; j < 256; j++) { unsigned v = part[j]; part[j] = run; run += v; }
    }
    __syncthreads();
    unsigned p = part[t];
#pragma unroll
    for (int k = 0; k < 4; k++) {
        int idx = t * 4 + k;
        if (idx < nb) binBase[idx] = p + loc[k];
    }
    if (t == 255) binBase[nb] = p + s;
}

// single-pass placement, zero global atomics: sbase from binBase+chunkOfsT
// (coalesced), local order via LDS atomic, scattered 8B store (run-local
// frontier ~84B/bin). int4/float4 edge loads.
__global__ __launch_bounds__(1024) void binscatter_kernel(
        const int* __restrict__ src, const int* __restrict__ dst,
        const float* __restrict__ ew, const unsigned* __restrict__ binBase,
        const unsigned* __restrict__ chunkOfsT,
        uint2* __restrict__ binned, int e, int nb) {
    __shared__ unsigned cnt[NB_MAX];
    __shared__ unsigned sbase[NB_MAX];
    const int c = blockIdx.x;
    const int t = threadIdx.x;
    for (int b = t; b < nb; b += 1024) {
        cnt[b] = 0u;
        sbase[b] = binBase[b] + chunkOfsT[(long)c * nb + b];  // coalesced
    }
    __syncthreads();
    const long base = (long)c * CHUNK;
#pragma unroll
    for (int k = 0; k < CHUNK / 4096; k++) {               // 2 iters of int4
        long i = base + ((long)k * 1024 + t) * 4;
        if (i + 3 < e) {
            int4 d4 = *(const int4*)(dst + i);
            int4 s4 = *(const int4*)(src + i);
            float4 w4 = *(const float4*)(ew + i);
            int dd[4] = {d4.x, d4.y, d4.z, d4.w};
            int ss[4] = {s4.x, s4.y, s4.z, s4.w};
            float ww[4] = {w4.x, w4.y, w4.z, w4.w};
#pragma unroll
            for (int j = 0; j < 4; j++) {
                int b = dd[j] >> BINSHIFT;
                unsigned p = sbase[b] + atomicAdd(&cnt[b], 1u);
                binned[p] = uint2{(unsigned)ss[j] | ((unsigned)(dd[j] & (BINW - 1)) << 20),
                                  __float_as_uint(ww[j])};
            }
        } else {
            for (int j = 0; j < 4; j++) {
                long i2 = i + j;
                if (i2 < e) {
                    int d = dst[i2];
                    int b = d >> BINSHIFT;
                    unsigned p = sbase[b] + atomicAdd(&cnt[b], 1u);
                    binned[p] = uint2{(unsigned)src[i2] | ((unsigned)(d & (BINW - 1)) << 20),
                                      __float_as_uint(ew[i2])};
                }
            }
        }
    }
}

// per bin: wsum[dlow] += ew (LDS f32 atomics) -> dis; disA = dis;
// v1 = dis*q; tpart = c1 + dis^2 q
__global__ __launch_bounds__(256) void setup_kernel(
        const uint2* __restrict__ binned, const unsigned* __restrict__ binBase,
        const double* __restrict__ cvals, const double* __restrict__ q,
        float* __restrict__ disA, double* __restrict__ v1,
        double* __restrict__ tpart, int n) {
    __shared__ float ws[BINW];
    const int b = blockIdx.x;
    const int t = threadIdx.x;
    if (t < BINW) ws[t] = 0.0f;
    __syncthreads();
    const unsigned s0 = binBase[b], s1 = binBase[b + 1];
    for (unsigned i = s0 + t; i < s1; i += 256) {
        uint2 v = binned[i];
        atomicAdd(&ws[v.x >> 20], __uint_as_float(v.y));
    }
    __syncthreads();
    if (t < BINW) {
        int node = b * BINW + t;
        if (node < n) {
            float d = 1.0f + ws[t];  // self-loop weight 1
            float di = (d > 0.0f) ? (1.0f / sqrtf(fmaxf(d, 1e-12f))) : 0.0f;
            double qv = q[node];
            disA[node] = di;
            v1[node] = (double)di * qv;
            tpart[node] = cvals[1] + (double)(di * di) * qv;
        }
    }
}

// 512-thr block per bin: 4 LDS sub-accumulators (per 128-thr group) kill
// contention; 8 waves/block doubles gather concurrency (12 -> 24 waves/CU).
// acc[sub][dlow] += ew * v1[s]; epilogue combines subs: v2 = dis*(tpart+dis*S)
__global__ __launch_bounds__(512) void spmv1_kernel(
        const uint2* __restrict__ binned, const unsigned* __restrict__ binBase,
        const double* __restrict__ v1, const float* __restrict__ disA,
        const double* __restrict__ tpart, double* __restrict__ v2, int n) {
    __shared__ double acc[4][BINW];
    const int b = blockIdx.x;
    const int t = threadIdx.x;
    const int sub = t >> 7;
    {
        double* f = &acc[0][0];
        if (t < 512) f[t] = 0.0;  // 4*128 = 512 doubles
    }
    __syncthreads();
    const unsigned s0 = binBase[b], s1 = binBase[b + 1];
    for (unsigned tile = s0; tile < s1; tile += 2048) {
        uint2 ee[4];
        double vv[4];
        bool ok[4];
#pragma unroll
        for (int k = 0; k < 4; k++) {
            unsigned idx = tile + t + k * 512u;
            ok[k] = (idx < s1);
            if (ok[k]) ee[k] = binned[idx];             // coalesced 8B
        }
#pragma unroll
        for (int k = 0; k < 4; k++)
            if (ok[k]) vv[k] = v1[ee[k].x & 0xFFFFFu];  // scattered 8B gather
#pragma unroll
        for (int k = 0; k < 4; k++)
            if (ok[k])
                atomicAdd(&acc[sub][ee[k].x >> 20],
                          (double)__uint_as_float(ee[k].y) * vv[k]);
    }
    __syncthreads();
    if (t < BINW) {
        int node = b * BINW + t;
        if (node < n) {
            double S = acc[0][t] + acc[1][t] + acc[2][t] + acc[3][t];
            double di = (double)disA[node];
            v2[node] = di * (tpart[node] + di * S);
        }
    }
}

// same structure: acc[sub][dlow] += ew * v2[s]; u = c0 + dis*(v2 + S)
__global__ __launch_bounds__(512) void spmv2_head_kernel(
        const uint2* __restrict__ binned, const unsigned* __restrict__ binBase,
        const double* __restrict__ v2, const float* __restrict__ disA,
        const double* __restrict__ cvals, float* __restrict__ out, int n) {
    __shared__ double acc[4][BINW];
    const int b = blockIdx.x;
    const int t = threadIdx.x;
    const int sub = t >> 7;
    {
        double* f = &acc[0][0];
        if (t < 512) f[t] = 0.0;
    }
    __syncthreads();
    const unsigned s0 = binBase[b], s1 = binBase[b + 1];
    for (unsigned tile = s0; tile < s1; tile += 2048) {
        uint2 ee[4];
        double vv[4];
        bool ok[4];
#pragma unroll
        for (int k = 0; k < 4; k++) {
            unsigned idx = tile + t + k * 512u;
            ok[k] = (idx < s1);
            if (ok[k]) ee[k] = binned[idx];
        }
#pragma unroll
        for (int k = 0; k < 4; k++)
            if (ok[k]) vv[k] = v2[ee[k].x & 0xFFFFFu];
#pragma unroll
        for (int k = 0; k < 4; k++)
            if (ok[k])
                atomicAdd(&acc[sub][ee[k].x >> 20],
                          (double)__uint_as_float(ee[k].y) * vv[k]);
    }
    __syncthreads();
    if (t < BINW) {
        int node = b * BINW + t;
        if (node < n) {
            double S = acc[0][t] + acc[1][t] + acc[2][t] + acc[3][t];
            double u = cvals[0] + (double)disA[node] * (v2[node] + S);
            float o = (float)u;
            o = fminf(fmaxf(o, 0.0f), 10.0f);
            out[node] = rintf(o);  // v_rndne_f32: half-to-even, matches jnp.round
        }
    }
}

extern "C" void kernel_launch(void* const* d_in, const int* in_sizes, int n_in,
                              void* d_out, int out_size, void* d_ws, size_t ws_size,
                              hipStream_t stream) {
    const float* x   = (const float*)d_in[0];  // [N, 128]
    const int*   eix = (const int*)d_in[1];    // [2, E]
    const float* ew  = (const float*)d_in[2];  // [E]
    const float* W1  = (const float*)d_in[3];  // [128, 64]
    const float* b1  = (const float*)d_in[4];  // [64]
    const float* W2  = (const float*)d_in[5];  // [64, 64]
    const float* b2  = (const float*)d_in[6];  // [64]
    const float* fcw = (const float*)d_in[7];  // [64]
    const float* fcb = (const float*)d_in[8];  // [1]
    float* out = (float*)d_out;                // [N]

    const int n = in_sizes[0] / DIN;
    const int e = in_sizes[2];
    const int* src = eix;
    const int* dst = eix + e;
    const int nb = (n + BINW - 1) / BINW;            // 782 bins at n=100000
    const int hblk = (e + CHUNK - 1) / CHUNK;        // 196 chunks

    // workspace layout (8-byte units, 64-unit aligned regions); ~18 MB
    auto al = [](size_t v) { return (v + 63) & ~(size_t)63; };
    double* ws = (double*)d_ws;
    size_t o = 0;
    double*   w1f     = ws + o; o += al(DIN);
    double*   cvals   = ws + o; o += al(2);
    double*   q       = ws + o; o += al((size_t)n);
    double*   tpart   = ws + o; o += al((size_t)n);
    double*   v1      = ws + o; o += al((size_t)n);
    double*   v2      = ws + o; o += al((size_t)n);
    float*    disA    = (float*)(ws + o);    o += al(((size_t)n + 1) / 2);
    unsigned* binCnt  = (unsigned*)(ws + o); o += al(((size_t)nb + 1) / 2);
    unsigned* binBase = (unsigned*)(ws + o); o += al(((size_t)nb + 2) / 2);
    unsigned* histT   = (unsigned*)(ws + o); o += al(((size_t)nb * hblk + 1) / 2);
    unsigned* chunkOfsT = (unsigned*)(ws + o); o += al(((size_t)nb * hblk + 1) / 2);
    uint2*    binned  = (uint2*)(ws + o);   // e * 8B = 12.8 MB

    const int gemvblk = (n + 7) / 8;                 // 2 rows/wave, 4 waves/block
    const int bsblk = (nb * 64 + 255) / 256;         // binscan: wave per bin

    precompute_kernel<<<1, 256, 0, stream>>>(W1, b1, W2, b2, fcw, fcb, w1f, cvals);
    hist_gemv_kernel<<<hblk + gemvblk, 256, 0, stream>>>(dst, x, w1f, histT,
                                                         q, n, e, nb, hblk);
    binscan_kernel<<<bsblk, 256, 0, stream>>>(histT, chunkOfsT, binCnt, nb, hblk);
    scan_kernel<<<1, 256, 0, stream>>>(binCnt, binBase, nb);
    binscatter_kernel<<<hblk, 1024, 0, stream>>>(src, dst, ew, binBase, chunkOfsT,
                                                 binned, e, nb);
    setup_kernel<<<nb, 256, 0, stream>>>(binned, binBase, cvals, q, disA, v1,
                                         tpart, n);
    spmv1_kernel<<<nb, 512, 0, stream>>>(binned, binBase, v1, disA, tpart, v2, n);
    spmv2_head_kernel<<<nb, 512, 0, stream>>>(binned, binBase, v2, disA, cvals,
                                              out, n);
}